// Round 1
// baseline (438.351 us; speedup 1.0000x reference)
//
#include <hip/hip_runtime.h>
#include <math.h>

#define NOP 4096
#define NTASK 64
#define NTENSOR 32768
#define NLINK 1024
#define NPLACE (NOP*NTASK)
#define RAWOP 256
#define RAWE 16
#define EH 8

// ---- workspace layout (units of 4 bytes) ----
enum : int {
  O_CNT_PREV  = 0,
  O_CNT_SUCC  = O_CNT_PREV + NOP,
  O_CNT_LINK  = O_CNT_SUCC + NOP,          // 64
  O_SEF_PREV  = O_CNT_LINK + 64,           // NOP*8
  O_SEF_SUCC  = O_SEF_PREV + NOP*8,
  O_SEF_LINK  = O_SEF_SUCC + NOP*8,        // 64*8
  O_SEF_PLACE = O_SEF_LINK + 64*8,         // 64*8
  O_MEANOP    = O_SEF_PLACE + 64*8,        // 6*64 (sums over ops entering layer l)
  O_MEANTASK  = O_MEANOP + 6*64,           // 6*64
  O_ZERO_END  = O_MEANTASK + 6*64,
  O_OP_A      = O_ZERO_END,                // NOP*64
  O_OP_B      = O_OP_A + NOP*64,
  O_TASK_A    = O_OP_B + NOP*64,           // 64*64
  O_TASK_B    = O_TASK_A + 64*64,
  O_SEF_SERVE = O_TASK_B + 64*64,          // NOP*8
  O_BPLACE    = O_SEF_SERVE + NOP*8,       // NPLACE
  O_RP_PREV   = O_BPLACE + NPLACE,         // NOP+1
  O_RP_SUCC   = O_RP_PREV + NOP + 1,
  O_RP_LINK   = O_RP_SUCC + NOP + 1,       // 65
  O_FILL_PREV = O_RP_LINK + 65,            // NOP
  O_FILL_SUCC = O_FILL_PREV + NOP,
  O_FILL_LINK = O_FILL_SUCC + NOP,         // 64
  O_CSR_PREV  = O_FILL_LINK + 64,          // NTENSOR (stores src per edge)
  O_CSR_SUCC  = O_CSR_PREV + NTENSOR,
  O_CSR_LINK  = O_CSR_SUCC + NTENSOR,      // NLINK
  O_TOTAL     = O_CSR_LINK + NLINK
};

__device__ __forceinline__ float elu1(float x) { return x > 0.f ? x : expm1f(x); }

__device__ __forceinline__ void fma4(float4& a, const float s, const float4 w) {
  a.x = fmaf(s, w.x, a.x);
  a.y = fmaf(s, w.y, a.y);
  a.z = fmaf(s, w.z, a.z);
  a.w = fmaf(s, w.w, a.w);
}

// ---------------- op embedding: [4096,256]@[256,64] + elu ----------------
__global__ __launch_bounds__(256) void k_op_embed(
    const float* __restrict__ A, const float* __restrict__ W, const float* __restrict__ b,
    float* __restrict__ out, float* __restrict__ meanop0)
{
  __shared__ float sW[8192];       // half of W (128 rows x 64)
  __shared__ float sA[16*260];     // 16 op rows, padded stride 260
  __shared__ float4 red[256];
  const int tid = threadIdx.x;
  const int obase = blockIdx.x * 16;
  for (int i = tid; i < 4096; i += 256) {
    const int o = i >> 8, k = i & 255;
    sA[o*260 + k] = A[(size_t)(obase + o)*256 + k];
  }
  const int o = tid >> 4, hq = tid & 15, h0 = hq*4;
  float4 acc = *(const float4*)&b[h0];
  for (int half = 0; half < 2; ++half) {
    __syncthreads();
    for (int i = tid*4; i < 8192; i += 1024)
      *(float4*)&sW[i] = *(const float4*)&W[half*8192 + i];
    __syncthreads();
    const float* a = &sA[o*260 + half*128];
    for (int k = 0; k < 128; ++k)
      fma4(acc, a[k], *(const float4*)&sW[k*64 + h0]);
  }
  acc.x = elu1(acc.x); acc.y = elu1(acc.y); acc.z = elu1(acc.z); acc.w = elu1(acc.w);
  *(float4*)&out[(size_t)(obase + o)*64 + h0] = acc;
  red[tid] = acc;
  __syncthreads();
  if (tid < 16) {
    float4 s = make_float4(0.f,0.f,0.f,0.f);
    for (int g = 0; g < 16; ++g) {
      float4 v = red[g*16 + tid];
      s.x += v.x; s.y += v.y; s.z += v.z; s.w += v.w;
    }
    atomicAdd(&meanop0[tid*4+0], s.x);
    atomicAdd(&meanop0[tid*4+1], s.y);
    atomicAdd(&meanop0[tid*4+2], s.z);
    atomicAdd(&meanop0[tid*4+3], s.w);
  }
}

// ---------------- task embedding: [64,64]@[64,64] + elu ----------------
__global__ __launch_bounds__(256) void k_task_embed(
    const float* __restrict__ A, const float* __restrict__ W, const float* __restrict__ b,
    float* __restrict__ out, float* __restrict__ meantask0)
{
  __shared__ float sA[64*65];
  __shared__ float sW[64*64];
  __shared__ float4 red[256];
  const int tid = threadIdx.x;
  for (int i = tid; i < 4096; i += 256) {
    const int t = i >> 6, k = i & 63;
    sA[t*65 + k] = A[i];
  }
  for (int i = tid*4; i < 4096; i += 1024)
    *(float4*)&sW[i] = *(const float4*)&W[i];
  __syncthreads();
  const int og = tid >> 4, hq = tid & 15, h0 = hq*4;
  float4 msum = make_float4(0.f,0.f,0.f,0.f);
  for (int tg = 0; tg < 4; ++tg) {
    const int t = tg*16 + og;
    float4 acc = *(const float4*)&b[h0];
    const float* a = &sA[t*65];
    for (int k = 0; k < 64; ++k)
      fma4(acc, a[k], *(const float4*)&sW[k*64 + h0]);
    acc.x = elu1(acc.x); acc.y = elu1(acc.y); acc.z = elu1(acc.z); acc.w = elu1(acc.w);
    *(float4*)&out[t*64 + h0] = acc;
    msum.x += acc.x; msum.y += acc.y; msum.z += acc.z; msum.w += acc.w;
  }
  red[tid] = msum;
  __syncthreads();
  if (tid < 16) {
    float4 s = make_float4(0.f,0.f,0.f,0.f);
    for (int g = 0; g < 16; ++g) {
      float4 v = red[g*16 + tid];
      s.x += v.x; s.y += v.y; s.z += v.z; s.w += v.w;
    }
    atomicAdd(&meantask0[tid*4+0], s.x);
    atomicAdd(&meantask0[tid*4+1], s.y);
    atomicAdd(&meantask0[tid*4+2], s.z);
    atomicAdd(&meantask0[tid*4+3], s.w);
  }
}

// ------------- tensor + link edges: ef sums per dst, degree counts -------------
__global__ __launch_bounds__(256) void k_edge_pass1(
    const float* __restrict__ tensor_feats, const float* __restrict__ link_feats,
    const int* __restrict__ prev_src, const int* __restrict__ prev_dst,
    const int* __restrict__ link_src, const int* __restrict__ link_dst,
    const float* __restrict__ eW, const float* __restrict__ eb,
    float* __restrict__ ws)
{
  __shared__ float sEW[640];
  __shared__ float sEB[40];
  const int tid = threadIdx.x;
  for (int i = tid; i < 640; i += 256) sEW[i] = eW[i];
  if (tid < 40) sEB[tid] = eb[tid];
  __syncthreads();
  int* ib = (int*)ws;
  const int e = blockIdx.x*256 + tid;
  float raw[16];
  *(float4*)&raw[0]  = *(const float4*)&tensor_feats[(size_t)e*16 + 0];
  *(float4*)&raw[4]  = *(const float4*)&tensor_feats[(size_t)e*16 + 4];
  *(float4*)&raw[8]  = *(const float4*)&tensor_feats[(size_t)e*16 + 8];
  *(float4*)&raw[12] = *(const float4*)&tensor_feats[(size_t)e*16 + 12];
  float efp[8], efs[8];
#pragma unroll
  for (int c = 0; c < 8; ++c) { efp[c] = sEB[8+c]; efs[c] = sEB[16+c]; }
#pragma unroll
  for (int k = 0; k < 16; ++k) {
    const float a = raw[k];
#pragma unroll
    for (int c = 0; c < 8; ++c) {
      efp[c] = fmaf(a, sEW[128 + k*8 + c], efp[c]);
      efs[c] = fmaf(a, sEW[256 + k*8 + c], efs[c]);
    }
  }
  const int pd = prev_dst[e], ps = prev_src[e];
  float* sefp = ws + O_SEF_PREV;
  float* sefs = ws + O_SEF_SUCC;
#pragma unroll
  for (int c = 0; c < 8; ++c) atomicAdd(&sefp[pd*8 + c], elu1(efp[c]));
#pragma unroll
  for (int c = 0; c < 8; ++c) atomicAdd(&sefs[ps*8 + c], elu1(efs[c]));
  atomicAdd(&ib[O_CNT_PREV + pd], 1);
  atomicAdd(&ib[O_CNT_SUCC + ps], 1);
  if (e < NLINK) {
    float rl[16];
    *(float4*)&rl[0]  = *(const float4*)&link_feats[(size_t)e*16 + 0];
    *(float4*)&rl[4]  = *(const float4*)&link_feats[(size_t)e*16 + 4];
    *(float4*)&rl[8]  = *(const float4*)&link_feats[(size_t)e*16 + 8];
    *(float4*)&rl[12] = *(const float4*)&link_feats[(size_t)e*16 + 12];
    float efl[8];
#pragma unroll
    for (int c = 0; c < 8; ++c) efl[c] = sEB[c];
#pragma unroll
    for (int k = 0; k < 16; ++k) {
      const float a = rl[k];
#pragma unroll
      for (int c = 0; c < 8; ++c) efl[c] = fmaf(a, sEW[k*8 + c], efl[c]);
    }
    const int ld = link_dst[e];
    float* sefl = ws + O_SEF_LINK;
#pragma unroll
    for (int c = 0; c < 8; ++c) atomicAdd(&sefl[ld*8 + c], elu1(efl[c]));
    atomicAdd(&ib[O_CNT_LINK + ld], 1);
  }
}

// ------------- prefix sums -> CSR row pointers (+fill cursors) -------------
__global__ __launch_bounds__(1024) void k_scan(float* __restrict__ ws)
{
  __shared__ int s[1024];
  const int tid = threadIdx.x;
  int* ib = (int*)ws;
  for (int which = 0; which < 2; ++which) {
    const int* cnt = ib + (which == 0 ? O_CNT_PREV : O_CNT_SUCC);
    int* rp = ib + (which == 0 ? O_RP_PREV : O_RP_SUCC);
    int* fl = ib + (which == 0 ? O_FILL_PREV : O_FILL_SUCC);
    const int c0 = cnt[tid*4+0], c1 = cnt[tid*4+1], c2 = cnt[tid*4+2], c3 = cnt[tid*4+3];
    const int mysum = c0 + c1 + c2 + c3;
    s[tid] = mysum;
    __syncthreads();
    for (int off = 1; off < 1024; off <<= 1) {
      int v = (tid >= off) ? s[tid-off] : 0;
      __syncthreads();
      s[tid] += v;
      __syncthreads();
    }
    int run = s[tid] - mysum;
    rp[tid*4+0] = run; fl[tid*4+0] = run; run += c0;
    rp[tid*4+1] = run; fl[tid*4+1] = run; run += c1;
    rp[tid*4+2] = run; fl[tid*4+2] = run; run += c2;
    rp[tid*4+3] = run; fl[tid*4+3] = run; run += c3;
    if (tid == 1023) rp[4096] = run;
    __syncthreads();
  }
  if (tid == 0) {
    const int* cnt = ib + O_CNT_LINK;
    int* rp = ib + O_RP_LINK;
    int* fl = ib + O_FILL_LINK;
    int run = 0;
    for (int t = 0; t < 64; ++t) { rp[t] = run; fl[t] = run; run += cnt[t]; }
    rp[64] = run;
  }
}

// ------------- CSR fill (stores the SOURCE node index per edge slot) -------------
__global__ __launch_bounds__(256) void k_fill(
    const int* __restrict__ prev_src, const int* __restrict__ prev_dst,
    const int* __restrict__ link_src, const int* __restrict__ link_dst,
    float* __restrict__ ws)
{
  int* ib = (int*)ws;
  const int e = blockIdx.x*256 + threadIdx.x;
  const int pd = prev_dst[e], ps = prev_src[e];
  int pos = atomicAdd(&ib[O_FILL_PREV + pd], 1);
  ib[O_CSR_PREV + pos] = ps;
  int pos2 = atomicAdd(&ib[O_FILL_SUCC + ps], 1);
  ib[O_CSR_SUCC + pos2] = pd;
  if (e < NLINK) {
    const int ld = link_dst[e];
    int p3 = atomicAdd(&ib[O_FILL_LINK + ld], 1);
    ib[O_CSR_LINK + p3] = link_src[e];
  }
}

// ------------- place/serve pass: ef sums + final-head b term -------------
__global__ __launch_bounds__(256) void k_place(
    const float* __restrict__ place_feats, const float* __restrict__ eW,
    const float* __restrict__ eb, const float* __restrict__ finalW,
    float* __restrict__ ws)
{
  __shared__ float sW3[128], sW4[128], sB3[8], sB4[8], sW1[8];
  __shared__ float pl[512];
  const int tid = threadIdx.x;
  if (tid < 128) { sW3[tid] = eW[3*128 + tid]; sW4[tid] = eW[4*128 + tid]; }
  if (tid < 8) { sB3[tid] = eb[24+tid]; sB4[tid] = eb[32+tid]; sW1[tid] = finalW[64+tid]; }
  for (int i = tid; i < 512; i += 256) pl[i] = 0.f;
  __syncthreads();
  const int lane = tid & 63;
  const int wave = (blockIdx.x*256 + tid) >> 6;   // 0..1023, 4 ops each
  float pacc[8];
#pragma unroll
  for (int c = 0; c < 8; ++c) pacc[c] = 0.f;
  float* bplace = ws + O_BPLACE;
  float* sserve = ws + O_SEF_SERVE;
  for (int j = 0; j < 4; ++j) {
    const int i = wave*4 + j;
    const int e = i*64 + lane;
    float raw[16];
    *(float4*)&raw[0]  = *(const float4*)&place_feats[(size_t)e*16 + 0];
    *(float4*)&raw[4]  = *(const float4*)&place_feats[(size_t)e*16 + 4];
    *(float4*)&raw[8]  = *(const float4*)&place_feats[(size_t)e*16 + 8];
    *(float4*)&raw[12] = *(const float4*)&place_feats[(size_t)e*16 + 12];
    float efp[8], efs[8];
#pragma unroll
    for (int c = 0; c < 8; ++c) { efp[c] = sB3[c]; efs[c] = sB4[c]; }
#pragma unroll
    for (int k = 0; k < 16; ++k) {
      const float a = raw[k];
#pragma unroll
      for (int c = 0; c < 8; ++c) {
        efp[c] = fmaf(a, sW3[k*8 + c], efp[c]);
        efs[c] = fmaf(a, sW4[k*8 + c], efs[c]);
      }
    }
    float bp = 0.f;
#pragma unroll
    for (int c = 0; c < 8; ++c) {
      efp[c] = elu1(efp[c]);
      efs[c] = elu1(efs[c]);
      bp = fmaf(efp[c], sW1[c], bp);
      pacc[c] += efp[c];
    }
    bplace[e] = bp;
#pragma unroll
    for (int c = 0; c < 8; ++c) {
      float v = efs[c];
      for (int m = 32; m >= 1; m >>= 1) v += __shfl_xor(v, m, 64);
      if (lane == 0) sserve[i*8 + c] = v;
    }
  }
#pragma unroll
  for (int c = 0; c < 8; ++c) atomicAdd(&pl[lane*8 + c], pacc[c]);
  __syncthreads();
  float* spl = ws + O_SEF_PLACE;
  for (int i = tid; i < 512; i += 256) atomicAdd(&spl[i], pl[i]);
}

// ------------- one GNN layer: blocks 0..255 update ops, 256..259 tasks -------------
__global__ __launch_bounds__(256) void k_layer(
    const int l,
    const float* __restrict__ gW, const float* __restrict__ gb,
    const float* __restrict__ op_in, float* __restrict__ op_out,
    const float* __restrict__ task_in, float* __restrict__ task_out,
    float* __restrict__ ws)
{
  __shared__ float smem[13056];
  const int tid = threadIdx.x;
  const int bid = blockIdx.x;
  const int* ib = (const int*)ws;
  const int* rp_prev = ib + O_RP_PREV;
  const int* rp_succ = ib + O_RP_SUCC;
  const int* rp_link = ib + O_RP_LINK;
  const int* csr_prev = ib + O_CSR_PREV;
  const int* csr_succ = ib + O_CSR_SUCC;
  const int* csr_link = ib + O_CSR_LINK;

  if (bid < 256) {
    // ---------------- op update ----------------
    float* sWp    = smem;            // 4096 node-W prev
    float* sWep   = smem + 4096;     // 512 edge-W prev (contiguous w/ sWp in gW)
    float* sWs    = smem + 4608;     // 4096 node-W succ
    float* sWes   = smem + 8704;     // 512
    float* sWeS   = smem + 9216;     // 512 edge-W serve
    float* sGBp   = smem + 9728;     // 64
    float* sGBs   = smem + 9792;     // 64
    float* vserve = smem + 9856;     // 64
    float* sums_p = smem + 9920;     // 16 x 65
    float* sums_s = smem + 10960;    // 16 x 65
    float4* red   = (float4*)(smem + 12000);

    const float* gWprev  = gW + (size_t)((6  + l)*72)*64;
    const float* gWsucc  = gW + (size_t)((12 + l)*72)*64;
    const float* gWserve = gW + (size_t)((24 + l)*72)*64;
    for (int i = tid*4; i < 4608; i += 1024) {
      *(float4*)&sWp[i] = *(const float4*)&gWprev[i];
      *(float4*)&sWs[i] = *(const float4*)&gWsucc[i];
    }
    for (int i = tid*4; i < 512; i += 1024)
      *(float4*)&sWeS[i] = *(const float4*)&gWserve[4096 + i];
    if (tid < 64) {
      sGBp[tid] = gb[(6+l)*64 + tid];
      sGBs[tid] = gb[(12+l)*64 + tid];
      const float* mt = ws + O_MEANTASK + l*64;
      float acc = gb[(24+l)*64 + tid];
      for (int k = 0; k < 64; ++k)
        acc = fmaf(mt[k]*(1.f/64.f), gWserve[k*64 + tid], acc);
      vserve[tid] = acc;
    }
    __syncthreads();
    const int obase = bid*16;
    {
      const int wave = tid >> 6, lane = tid & 63;
      for (int jo = 0; jo < 4; ++jo) {
        const int o = wave*4 + jo;
        const int d = obase + o;
        float sp = 0.f;
        const int pb = rp_prev[d], pe = rp_prev[d+1];
        for (int p = pb; p < pe; ++p) sp += op_in[(size_t)csr_prev[p]*64 + lane];
        float ss = 0.f;
        const int sb = rp_succ[d], se2 = rp_succ[d+1];
        for (int p = sb; p < se2; ++p) ss += op_in[(size_t)csr_succ[p]*64 + lane];
        sums_p[o*65 + lane] = sp;
        sums_s[o*65 + lane] = ss;
      }
    }
    __syncthreads();
    const int o = tid >> 4, hq = tid & 15, h0 = hq*4;
    const int d = obase + o;
    float4 up = make_float4(0.f,0.f,0.f,0.f);
    float4 us = make_float4(0.f,0.f,0.f,0.f);
    const int cp = rp_prev[d+1] - rp_prev[d];
    if (cp > 0) {
      float4 acc = make_float4(0.f,0.f,0.f,0.f);
      for (int k = 0; k < 64; ++k)
        fma4(acc, sums_p[o*65 + k], *(const float4*)&sWp[k*64 + h0]);
      const float* se = ws + O_SEF_PREV + d*8;
#pragma unroll
      for (int c = 0; c < 8; ++c)
        fma4(acc, se[c], *(const float4*)&sWep[c*64 + h0]);
      const float r = 1.f/(float)cp;
      up.x = fmaf(acc.x, r, sGBp[h0+0]);
      up.y = fmaf(acc.y, r, sGBp[h0+1]);
      up.z = fmaf(acc.z, r, sGBp[h0+2]);
      up.w = fmaf(acc.w, r, sGBp[h0+3]);
    }
    const int cs = rp_succ[d+1] - rp_succ[d];
    if (cs > 0) {
      float4 acc = make_float4(0.f,0.f,0.f,0.f);
      for (int k = 0; k < 64; ++k)
        fma4(acc, sums_s[o*65 + k], *(const float4*)&sWs[k*64 + h0]);
      const float* se = ws + O_SEF_SUCC + d*8;
#pragma unroll
      for (int c = 0; c < 8; ++c)
        fma4(acc, se[c], *(const float4*)&sWes[c*64 + h0]);
      const float r = 1.f/(float)cs;
      us.x = fmaf(acc.x, r, sGBs[h0+0]);
      us.y = fmaf(acc.y, r, sGBs[h0+1]);
      us.z = fmaf(acc.z, r, sGBs[h0+2]);
      us.w = fmaf(acc.w, r, sGBs[h0+3]);
    }
    float4 ug = *(const float4*)&vserve[h0];
    {
      const float* se = ws + O_SEF_SERVE + d*8;
#pragma unroll
      for (int c = 0; c < 8; ++c)
        fma4(ug, se[c]*(1.f/64.f), *(const float4*)&sWeS[c*64 + h0]);
    }
    float4 x = *(const float4*)&op_in[(size_t)d*64 + h0];
    x.x = elu1(x.x + (up.x + us.x + ug.x)*(1.f/3.f));
    x.y = elu1(x.y + (up.y + us.y + ug.y)*(1.f/3.f));
    x.z = elu1(x.z + (up.z + us.z + ug.z)*(1.f/3.f));
    x.w = elu1(x.w + (up.w + us.w + ug.w)*(1.f/3.f));
    *(float4*)&op_out[(size_t)d*64 + h0] = x;
    if (l < 5) {
      red[tid] = x;
      __syncthreads();
      if (tid < 16) {
        float4 s = make_float4(0.f,0.f,0.f,0.f);
        for (int g = 0; g < 16; ++g) {
          float4 v = red[g*16 + tid];
          s.x += v.x; s.y += v.y; s.z += v.z; s.w += v.w;
        }
        float* mo = ws + O_MEANOP + (l+1)*64;
        atomicAdd(&mo[tid*4+0], s.x);
        atomicAdd(&mo[tid*4+1], s.y);
        atomicAdd(&mo[tid*4+2], s.z);
        atomicAdd(&mo[tid*4+3], s.w);
      }
    }
  } else {
    // ---------------- task update (4 blocks x 16 tasks) ----------------
    const int tbase = (bid - 256)*16;
    float* sTask  = smem;            // 4096
    float* sW0    = smem + 4096;     // 4096 node-W link
    float* sWe0   = smem + 8192;     // 512
    float* sWe3   = smem + 8704;     // 512 edge-W place
    float* sGB0   = smem + 9216;     // 64
    float* vplace = smem + 9280;     // 64
    float* sums_l = smem + 9344;     // 16 x 65
    float4* red   = (float4*)(smem + 10384);
    const float* gWlink  = gW + (size_t)(l*72)*64;
    const float* gWplace = gW + (size_t)((18 + l)*72)*64;
    for (int i = tid*4; i < 4096; i += 1024)
      *(float4*)&sTask[i] = *(const float4*)&task_in[i];
    for (int i = tid*4; i < 4608; i += 1024)
      *(float4*)&sW0[i] = *(const float4*)&gWlink[i];
    for (int i = tid*4; i < 512; i += 1024)
      *(float4*)&sWe3[i] = *(const float4*)&gWplace[4096 + i];
    if (tid < 64) {
      sGB0[tid] = gb[l*64 + tid];
      const float* mo = ws + O_MEANOP + l*64;
      float acc = gb[(18+l)*64 + tid];
      for (int k = 0; k < 64; ++k)
        acc = fmaf(mo[k]*(1.f/4096.f), gWplace[k*64 + tid], acc);
      vplace[tid] = acc;
    }
    __syncthreads();
    {
      const int wave = tid >> 6, lane = tid & 63;
      for (int jt = 0; jt < 4; ++jt) {
        const int tl = wave*4 + jt;
        const int t = tbase + tl;
        float s = 0.f;
        const int pb = rp_link[t], pe = rp_link[t+1];
        for (int p = pb; p < pe; ++p) s += sTask[csr_link[p]*64 + lane];
        sums_l[tl*65 + lane] = s;
      }
    }
    __syncthreads();
    const int tl = tid >> 4, hq = tid & 15, h0 = hq*4;
    const int t = tbase + tl;
    float4 ul = make_float4(0.f,0.f,0.f,0.f);
    const int cl2 = rp_link[t+1] - rp_link[t];
    if (cl2 > 0) {
      float4 acc = make_float4(0.f,0.f,0.f,0.f);
      for (int k = 0; k < 64; ++k)
        fma4(acc, sums_l[tl*65 + k], *(const float4*)&sW0[k*64 + h0]);
      const float* se = ws + O_SEF_LINK + t*8;
#pragma unroll
      for (int c = 0; c < 8; ++c)
        fma4(acc, se[c], *(const float4*)&sWe0[c*64 + h0]);
      const float r = 1.f/(float)cl2;
      ul.x = fmaf(acc.x, r, sGB0[h0+0]);
      ul.y = fmaf(acc.y, r, sGB0[h0+1]);
      ul.z = fmaf(acc.z, r, sGB0[h0+2]);
      ul.w = fmaf(acc.w, r, sGB0[h0+3]);
    }
    float4 uq = *(const float4*)&vplace[h0];
    {
      const float* sp = ws + O_SEF_PLACE + t*8;
#pragma unroll
      for (int c = 0; c < 8; ++c)
        fma4(uq, sp[c]*(1.f/4096.f), *(const float4*)&sWe3[c*64 + h0]);
    }
    float4 x = *(const float4*)&sTask[t*64 + h0];
    x.x = elu1(x.x + (ul.x + uq.x)*0.5f);
    x.y = elu1(x.y + (ul.y + uq.y)*0.5f);
    x.z = elu1(x.z + (ul.z + uq.z)*0.5f);
    x.w = elu1(x.w + (ul.w + uq.w)*0.5f);
    *(float4*)&task_out[t*64 + h0] = x;
    if (l < 5) {
      red[tid] = x;
      __syncthreads();
      if (tid < 16) {
        float4 s = make_float4(0.f,0.f,0.f,0.f);
        for (int g = 0; g < 16; ++g) {
          float4 v = red[g*16 + tid];
          s.x += v.x; s.y += v.y; s.z += v.z; s.w += v.w;
        }
        float* mt = ws + O_MEANTASK + (l+1)*64;
        atomicAdd(&mt[tid*4+0], s.x);
        atomicAdd(&mt[tid*4+1], s.y);
        atomicAdd(&mt[tid*4+2], s.z);
        atomicAdd(&mt[tid*4+3], s.w);
      }
    }
  }
}

// ------------- final head: out[i,t] = a_i + b_e + c_t + bias -------------
__global__ __launch_bounds__(256) void k_final(
    const float* __restrict__ opF, const float* __restrict__ taskF,
    const float* __restrict__ finalW, const float* __restrict__ finalb,
    const float* __restrict__ bplace, float* __restrict__ out)
{
  __shared__ float sTask[4096];
  __shared__ float cvec[64];
  const int tid = threadIdx.x;
  for (int i = tid*4; i < 4096; i += 1024)
    *(float4*)&sTask[i] = *(const float4*)&taskF[i];
  __syncthreads();
  const int lane = tid & 63;
  const int wave = tid >> 6;
  const float w2 = finalW[72 + lane];
  for (int jt = 0; jt < 16; ++jt) {
    const int t = wave*16 + jt;
    float v = sTask[t*64 + lane]*w2;
    for (int m = 32; m >= 1; m >>= 1) v += __shfl_xor(v, m, 64);
    if (lane == 0) cvec[t] = v;
  }
  __syncthreads();
  const int e = blockIdx.x*256 + tid;
  float v = opF[e]*finalW[lane];
  for (int m = 32; m >= 1; m >>= 1) v += __shfl_xor(v, m, 64);
  out[e] = v + bplace[e] + cvec[lane] + finalb[0];
}

extern "C" void kernel_launch(void* const* d_in, const int* in_sizes, int n_in,
                              void* d_out, int out_size, void* d_ws, size_t ws_size,
                              hipStream_t stream)
{
  (void)in_sizes; (void)n_in; (void)out_size;
  if (ws_size < (size_t)O_TOTAL * sizeof(float)) return;

  const float* op_feats     = (const float*)d_in[0];
  const float* task_feats   = (const float*)d_in[1];
  const float* tensor_feats = (const float*)d_in[2];
  const float* link_feats   = (const float*)d_in[3];
  const float* place_feats  = (const float*)d_in[4];
  const int*   prev_src     = (const int*)d_in[5];
  const int*   prev_dst     = (const int*)d_in[6];
  const int*   link_src     = (const int*)d_in[7];
  const int*   link_dst     = (const int*)d_in[8];
  const float* op_W         = (const float*)d_in[9];
  const float* op_b         = (const float*)d_in[10];
  const float* task_W       = (const float*)d_in[11];
  const float* task_b       = (const float*)d_in[12];
  const float* eW           = (const float*)d_in[13];
  const float* eb           = (const float*)d_in[14];
  const float* gW           = (const float*)d_in[15];
  const float* gb           = (const float*)d_in[16];
  const float* finalW       = (const float*)d_in[17];
  const float* finalb       = (const float*)d_in[18];
  float* w = (float*)d_ws;
  float* out = (float*)d_out;

  hipMemsetAsync(d_ws, 0, (size_t)O_ZERO_END * sizeof(float), stream);

  k_op_embed<<<256, 256, 0, stream>>>(op_feats, op_W, op_b, w + O_OP_A, w + O_MEANOP);
  k_task_embed<<<1, 256, 0, stream>>>(task_feats, task_W, task_b, w + O_TASK_A, w + O_MEANTASK);
  k_edge_pass1<<<128, 256, 0, stream>>>(tensor_feats, link_feats, prev_src, prev_dst,
                                        link_src, link_dst, eW, eb, w);
  k_scan<<<1, 1024, 0, stream>>>(w);
  k_fill<<<128, 256, 0, stream>>>(prev_src, prev_dst, link_src, link_dst, w);
  k_place<<<256, 256, 0, stream>>>(place_feats, eW, eb, finalW, w);

  for (int l = 0; l < 6; ++l) {
    const float* oin  = w + ((l & 1) ? O_OP_B : O_OP_A);
    float*       oout = w + ((l & 1) ? O_OP_A : O_OP_B);
    const float* tin  = w + ((l & 1) ? O_TASK_B : O_TASK_A);
    float*       tout = w + ((l & 1) ? O_TASK_A : O_TASK_B);
    k_layer<<<260, 256, 0, stream>>>(l, gW, gb, oin, oout, tin, tout, w);
  }

  k_final<<<1024, 256, 0, stream>>>(w + O_OP_A, w + O_TASK_A, finalW, finalb,
                                    w + O_BPLACE, out);
}

// Round 2
// 276.958 us; speedup vs baseline: 1.5827x; 1.5827x over previous
//
#include <hip/hip_runtime.h>
#include <math.h>

#define NOP 4096
#define NTASK 64
#define NTENSOR 32768
#define NLINK 1024
#define NPLACE (NOP*NTASK)
#define RAWOP 256
#define RAWE 16
#define EH 8
#define NOPB 512          // op-update blocks (8 ops each)
#define CAP_P 256         // LDS idx capacity per 8-op group per side (mean 64, ~24 sigma)
#define CAP_L 448         // LDS idx capacity per 16-task group (mean 256, ~12 sigma)

// ---- workspace layout (units of 4 bytes) ----
enum : int {
  O_CNT_PREV  = 0,
  O_CNT_SUCC  = O_CNT_PREV + NOP,
  O_CNT_LINK  = O_CNT_SUCC + NOP,          // 64
  O_SEF_PREV  = O_CNT_LINK + 64,           // NOP*8
  O_SEF_SUCC  = O_SEF_PREV + NOP*8,
  O_SEF_LINK  = O_SEF_SUCC + NOP*8,        // 64*8
  O_SEF_PLACE = O_SEF_LINK + 64*8,         // 64*8
  O_MEANOP    = O_SEF_PLACE + 64*8,        // 6*64 (sums over ops entering layer l)
  O_MEANTASK  = O_MEANOP + 6*64,           // 6*64
  O_ZERO_END  = O_MEANTASK + 6*64,
  O_OP_A      = O_ZERO_END,                // NOP*64
  O_OP_B      = O_OP_A + NOP*64,
  O_TASK_A    = O_OP_B + NOP*64,           // 64*64
  O_TASK_B    = O_TASK_A + 64*64,
  O_SEF_SERVE = O_TASK_B + 64*64,          // NOP*8
  O_BPLACE    = O_SEF_SERVE + NOP*8,       // NPLACE
  O_RP_PREV   = O_BPLACE + NPLACE,         // NOP+1
  O_RP_SUCC   = O_RP_PREV + NOP + 1,
  O_RP_LINK   = O_RP_SUCC + NOP + 1,       // 65
  O_FILL_PREV = O_RP_LINK + 65,            // NOP
  O_FILL_SUCC = O_FILL_PREV + NOP,
  O_FILL_LINK = O_FILL_SUCC + NOP,         // 64
  O_CSR_PREV  = O_FILL_LINK + 64,          // NTENSOR (stores src per edge)
  O_CSR_SUCC  = O_CSR_PREV + NTENSOR,
  O_CSR_LINK  = O_CSR_SUCC + NTENSOR,      // NLINK
  O_TOTAL     = O_CSR_LINK + NLINK
};

__device__ __forceinline__ float elu1(float x) { return x > 0.f ? x : expm1f(x); }

__device__ __forceinline__ void fma4(float4& a, const float s, const float4 w) {
  a.x = fmaf(s, w.x, a.x);
  a.y = fmaf(s, w.y, a.y);
  a.z = fmaf(s, w.z, a.z);
  a.w = fmaf(s, w.w, a.w);
}

// ---------------- op embedding: [4096,256]@[256,64] + elu ----------------
__global__ __launch_bounds__(256) void k_op_embed(
    const float* __restrict__ A, const float* __restrict__ W, const float* __restrict__ b,
    float* __restrict__ out, float* __restrict__ meanop0)
{
  __shared__ float sW[8192];       // half of W (128 rows x 64)
  __shared__ float sA[16*260];     // 16 op rows, padded stride 260
  __shared__ float4 red[256];
  const int tid = threadIdx.x;
  const int obase = blockIdx.x * 16;
  for (int i = tid; i < 4096; i += 256) {
    const int o = i >> 8, k = i & 255;
    sA[o*260 + k] = A[(size_t)(obase + o)*256 + k];
  }
  const int o = tid >> 4, hq = tid & 15, h0 = hq*4;
  float4 acc = *(const float4*)&b[h0];
  for (int half = 0; half < 2; ++half) {
    __syncthreads();
    for (int i = tid*4; i < 8192; i += 1024)
      *(float4*)&sW[i] = *(const float4*)&W[half*8192 + i];
    __syncthreads();
    const float* a = &sA[o*260 + half*128];
    for (int k = 0; k < 128; ++k)
      fma4(acc, a[k], *(const float4*)&sW[k*64 + h0]);
  }
  acc.x = elu1(acc.x); acc.y = elu1(acc.y); acc.z = elu1(acc.z); acc.w = elu1(acc.w);
  *(float4*)&out[(size_t)(obase + o)*64 + h0] = acc;
  red[tid] = acc;
  __syncthreads();
  if (tid < 16) {
    float4 s = make_float4(0.f,0.f,0.f,0.f);
    for (int g = 0; g < 16; ++g) {
      float4 v = red[g*16 + tid];
      s.x += v.x; s.y += v.y; s.z += v.z; s.w += v.w;
    }
    atomicAdd(&meanop0[tid*4+0], s.x);
    atomicAdd(&meanop0[tid*4+1], s.y);
    atomicAdd(&meanop0[tid*4+2], s.z);
    atomicAdd(&meanop0[tid*4+3], s.w);
  }
}

// ---------------- task embedding: [64,64]@[64,64] + elu ----------------
__global__ __launch_bounds__(256) void k_task_embed(
    const float* __restrict__ A, const float* __restrict__ W, const float* __restrict__ b,
    float* __restrict__ out, float* __restrict__ meantask0)
{
  __shared__ float sA[64*65];
  __shared__ float sW[64*64];
  __shared__ float4 red[256];
  const int tid = threadIdx.x;
  for (int i = tid; i < 4096; i += 256) {
    const int t = i >> 6, k = i & 63;
    sA[t*65 + k] = A[i];
  }
  for (int i = tid*4; i < 4096; i += 1024)
    *(float4*)&sW[i] = *(const float4*)&W[i];
  __syncthreads();
  const int og = tid >> 4, hq = tid & 15, h0 = hq*4;
  float4 msum = make_float4(0.f,0.f,0.f,0.f);
  for (int tg = 0; tg < 4; ++tg) {
    const int t = tg*16 + og;
    float4 acc = *(const float4*)&b[h0];
    const float* a = &sA[t*65];
    for (int k = 0; k < 64; ++k)
      fma4(acc, a[k], *(const float4*)&sW[k*64 + h0]);
    acc.x = elu1(acc.x); acc.y = elu1(acc.y); acc.z = elu1(acc.z); acc.w = elu1(acc.w);
    *(float4*)&out[t*64 + h0] = acc;
    msum.x += acc.x; msum.y += acc.y; msum.z += acc.z; msum.w += acc.w;
  }
  red[tid] = msum;
  __syncthreads();
  if (tid < 16) {
    float4 s = make_float4(0.f,0.f,0.f,0.f);
    for (int g = 0; g < 16; ++g) {
      float4 v = red[g*16 + tid];
      s.x += v.x; s.y += v.y; s.z += v.z; s.w += v.w;
    }
    atomicAdd(&meantask0[tid*4+0], s.x);
    atomicAdd(&meantask0[tid*4+1], s.y);
    atomicAdd(&meantask0[tid*4+2], s.z);
    atomicAdd(&meantask0[tid*4+3], s.w);
  }
}

// ------------- tensor + link edges: ef sums per dst, degree counts -------------
__global__ __launch_bounds__(256) void k_edge_pass1(
    const float* __restrict__ tensor_feats, const float* __restrict__ link_feats,
    const int* __restrict__ prev_src, const int* __restrict__ prev_dst,
    const int* __restrict__ link_src, const int* __restrict__ link_dst,
    const float* __restrict__ eW, const float* __restrict__ eb,
    float* __restrict__ ws)
{
  __shared__ float sEW[640];
  __shared__ float sEB[40];
  const int tid = threadIdx.x;
  for (int i = tid; i < 640; i += 256) sEW[i] = eW[i];
  if (tid < 40) sEB[tid] = eb[tid];
  __syncthreads();
  int* ib = (int*)ws;
  const int e = blockIdx.x*256 + tid;
  float raw[16];
  *(float4*)&raw[0]  = *(const float4*)&tensor_feats[(size_t)e*16 + 0];
  *(float4*)&raw[4]  = *(const float4*)&tensor_feats[(size_t)e*16 + 4];
  *(float4*)&raw[8]  = *(const float4*)&tensor_feats[(size_t)e*16 + 8];
  *(float4*)&raw[12] = *(const float4*)&tensor_feats[(size_t)e*16 + 12];
  float efp[8], efs[8];
#pragma unroll
  for (int c = 0; c < 8; ++c) { efp[c] = sEB[8+c]; efs[c] = sEB[16+c]; }
#pragma unroll
  for (int k = 0; k < 16; ++k) {
    const float a = raw[k];
#pragma unroll
    for (int c = 0; c < 8; ++c) {
      efp[c] = fmaf(a, sEW[128 + k*8 + c], efp[c]);
      efs[c] = fmaf(a, sEW[256 + k*8 + c], efs[c]);
    }
  }
  const int pd = prev_dst[e], ps = prev_src[e];
  float* sefp = ws + O_SEF_PREV;
  float* sefs = ws + O_SEF_SUCC;
#pragma unroll
  for (int c = 0; c < 8; ++c) atomicAdd(&sefp[pd*8 + c], elu1(efp[c]));
#pragma unroll
  for (int c = 0; c < 8; ++c) atomicAdd(&sefs[ps*8 + c], elu1(efs[c]));
  atomicAdd(&ib[O_CNT_PREV + pd], 1);
  atomicAdd(&ib[O_CNT_SUCC + ps], 1);
  if (e < NLINK) {
    float rl[16];
    *(float4*)&rl[0]  = *(const float4*)&link_feats[(size_t)e*16 + 0];
    *(float4*)&rl[4]  = *(const float4*)&link_feats[(size_t)e*16 + 4];
    *(float4*)&rl[8]  = *(const float4*)&link_feats[(size_t)e*16 + 8];
    *(float4*)&rl[12] = *(const float4*)&link_feats[(size_t)e*16 + 12];
    float efl[8];
#pragma unroll
    for (int c = 0; c < 8; ++c) efl[c] = sEB[c];
#pragma unroll
    for (int k = 0; k < 16; ++k) {
      const float a = rl[k];
#pragma unroll
      for (int c = 0; c < 8; ++c) efl[c] = fmaf(a, sEW[k*8 + c], efl[c]);
    }
    const int ld = link_dst[e];
    float* sefl = ws + O_SEF_LINK;
#pragma unroll
    for (int c = 0; c < 8; ++c) atomicAdd(&sefl[ld*8 + c], elu1(efl[c]));
    atomicAdd(&ib[O_CNT_LINK + ld], 1);
  }
}

// ------------- prefix sums -> CSR row pointers (+fill cursors) -------------
__global__ __launch_bounds__(1024) void k_scan(float* __restrict__ ws)
{
  __shared__ int s[1024];
  const int tid = threadIdx.x;
  int* ib = (int*)ws;
  for (int which = 0; which < 2; ++which) {
    const int* cnt = ib + (which == 0 ? O_CNT_PREV : O_CNT_SUCC);
    int* rp = ib + (which == 0 ? O_RP_PREV : O_RP_SUCC);
    int* fl = ib + (which == 0 ? O_FILL_PREV : O_FILL_SUCC);
    const int c0 = cnt[tid*4+0], c1 = cnt[tid*4+1], c2 = cnt[tid*4+2], c3 = cnt[tid*4+3];
    const int mysum = c0 + c1 + c2 + c3;
    s[tid] = mysum;
    __syncthreads();
    for (int off = 1; off < 1024; off <<= 1) {
      int v = (tid >= off) ? s[tid-off] : 0;
      __syncthreads();
      s[tid] += v;
      __syncthreads();
    }
    int run = s[tid] - mysum;
    rp[tid*4+0] = run; fl[tid*4+0] = run; run += c0;
    rp[tid*4+1] = run; fl[tid*4+1] = run; run += c1;
    rp[tid*4+2] = run; fl[tid*4+2] = run; run += c2;
    rp[tid*4+3] = run; fl[tid*4+3] = run; run += c3;
    if (tid == 1023) rp[4096] = run;
    __syncthreads();
  }
  if (tid == 0) {
    const int* cnt = ib + O_CNT_LINK;
    int* rp = ib + O_RP_LINK;
    int* fl = ib + O_FILL_LINK;
    int run = 0;
    for (int t = 0; t < 64; ++t) { rp[t] = run; fl[t] = run; run += cnt[t]; }
    rp[64] = run;
  }
}

// ------------- CSR fill (stores the SOURCE node index per edge slot) -------------
__global__ __launch_bounds__(256) void k_fill(
    const int* __restrict__ prev_src, const int* __restrict__ prev_dst,
    const int* __restrict__ link_src, const int* __restrict__ link_dst,
    float* __restrict__ ws)
{
  int* ib = (int*)ws;
  const int e = blockIdx.x*256 + threadIdx.x;
  const int pd = prev_dst[e], ps = prev_src[e];
  int pos = atomicAdd(&ib[O_FILL_PREV + pd], 1);
  ib[O_CSR_PREV + pos] = ps;
  int pos2 = atomicAdd(&ib[O_FILL_SUCC + ps], 1);
  ib[O_CSR_SUCC + pos2] = pd;
  if (e < NLINK) {
    const int ld = link_dst[e];
    int p3 = atomicAdd(&ib[O_FILL_LINK + ld], 1);
    ib[O_CSR_LINK + p3] = link_src[e];
  }
}

// ------------- place/serve pass: ef sums + final-head b term -------------
__global__ __launch_bounds__(256) void k_place(
    const float* __restrict__ place_feats, const float* __restrict__ eW,
    const float* __restrict__ eb, const float* __restrict__ finalW,
    float* __restrict__ ws)
{
  __shared__ float sW3[128], sW4[128], sB3[8], sB4[8], sW1[8];
  __shared__ float pl[512];
  const int tid = threadIdx.x;
  if (tid < 128) { sW3[tid] = eW[3*128 + tid]; sW4[tid] = eW[4*128 + tid]; }
  if (tid < 8) { sB3[tid] = eb[24+tid]; sB4[tid] = eb[32+tid]; sW1[tid] = finalW[64+tid]; }
  for (int i = tid; i < 512; i += 256) pl[i] = 0.f;
  __syncthreads();
  const int lane = tid & 63;
  const int wave = (blockIdx.x*256 + tid) >> 6;   // 0..1023, 4 ops each
  float pacc[8];
#pragma unroll
  for (int c = 0; c < 8; ++c) pacc[c] = 0.f;
  float* bplace = ws + O_BPLACE;
  float* sserve = ws + O_SEF_SERVE;
  for (int j = 0; j < 4; ++j) {
    const int i = wave*4 + j;
    const int e = i*64 + lane;
    float raw[16];
    *(float4*)&raw[0]  = *(const float4*)&place_feats[(size_t)e*16 + 0];
    *(float4*)&raw[4]  = *(const float4*)&place_feats[(size_t)e*16 + 4];
    *(float4*)&raw[8]  = *(const float4*)&place_feats[(size_t)e*16 + 8];
    *(float4*)&raw[12] = *(const float4*)&place_feats[(size_t)e*16 + 12];
    float efp[8], efs[8];
#pragma unroll
    for (int c = 0; c < 8; ++c) { efp[c] = sB3[c]; efs[c] = sB4[c]; }
#pragma unroll
    for (int k = 0; k < 16; ++k) {
      const float a = raw[k];
#pragma unroll
      for (int c = 0; c < 8; ++c) {
        efp[c] = fmaf(a, sW3[k*8 + c], efp[c]);
        efs[c] = fmaf(a, sW4[k*8 + c], efs[c]);
      }
    }
    float bp = 0.f;
#pragma unroll
    for (int c = 0; c < 8; ++c) {
      efp[c] = elu1(efp[c]);
      efs[c] = elu1(efs[c]);
      bp = fmaf(efp[c], sW1[c], bp);
      pacc[c] += efp[c];
    }
    bplace[e] = bp;
#pragma unroll
    for (int c = 0; c < 8; ++c) {
      float v = efs[c];
      for (int m = 32; m >= 1; m >>= 1) v += __shfl_xor(v, m, 64);
      if (lane == 0) sserve[i*8 + c] = v;
    }
  }
#pragma unroll
  for (int c = 0; c < 8; ++c) atomicAdd(&pl[lane*8 + c], pacc[c]);
  __syncthreads();
  float* spl = ws + O_SEF_PLACE;
  for (int i = tid; i < 512; i += 256) atomicAdd(&spl[i], pl[i]);
}

// ------------- one GNN layer -------------
// blocks 0..NOPB-1: update 8 ops each; blocks NOPB..NOPB+3: update 16 tasks each.
// Single barrier after staging; gather+matmul is per-wave (no cross-wave deps);
// one tail barrier for the mean reduction.
__global__ __launch_bounds__(256) void k_layer(
    const int l,
    const float* __restrict__ gW, const float* __restrict__ gb,
    const float* __restrict__ op_in, float* __restrict__ op_out,
    const float* __restrict__ task_in, float* __restrict__ task_out,
    float* __restrict__ ws)
{
  __shared__ float smem[12032];
  const int tid = threadIdx.x;
  const int bid = blockIdx.x;
  const int* ib = (const int*)ws;

  if (bid < NOPB) {
    // ---------------- op update: 8 ops ----------------
    float* sWp  = smem;             // 4608 (node 4096 + edge 512) prev
    float* sWs  = smem + 4608;      // 4608 succ
    float* sWeS = smem + 9216;      // 512 serve edge-W
    float* vp   = smem + 9728;      // 4x64 vserve partials
    float* sums_p = smem + 9984;    // 8 x 68
    float* sums_s = smem + 10528;   // 8 x 68
    float* sGB  = smem + 11072;     // 128 (prev bias, succ bias)
    float* sef  = smem + 11200;     // 192 (prev 64, succ 64, serve 64)
    float* mop  = smem + 11392;     // 64
    int* idxp_s = (int*)(smem + 11456);  // CAP_P
    int* idxs_s = (int*)(smem + 11456 + CAP_P);
    int* rpp_s  = (int*)(smem + 11456 + 2*CAP_P);       // 9
    int* rps_s  = (int*)(smem + 11456 + 2*CAP_P + 9);   // 9

    const int obase = bid*8;
    const float* gWprev  = gW + (size_t)((6  + l)*72)*64;
    const float* gWsucc  = gW + (size_t)((12 + l)*72)*64;
    const float* gWserve = gW + (size_t)((24 + l)*72)*64;

    // --- phase 0: stage everything (parallel, independent loads) ---
    for (int i = tid*4; i < 4608; i += 1024) {
      *(float4*)&sWp[i] = *(const float4*)&gWprev[i];
      *(float4*)&sWs[i] = *(const float4*)&gWsucc[i];
    }
    for (int i = tid*4; i < 512; i += 1024)
      *(float4*)&sWeS[i] = *(const float4*)&gWserve[4096 + i];
    if (tid < 9) {
      rpp_s[tid] = ib[O_RP_PREV + obase + tid];
      rps_s[tid] = ib[O_RP_SUCC + obase + tid];
    }
    {
      const int p0 = ib[O_RP_PREV + obase];
      const int np = min(ib[O_RP_PREV + obase + 8] - p0, CAP_P);
      for (int i = tid; i < np; i += 256) idxp_s[i] = ib[O_CSR_PREV + p0 + i];
      const int q0 = ib[O_RP_SUCC + obase];
      const int nq = min(ib[O_RP_SUCC + obase + 8] - q0, CAP_P);
      for (int i = tid; i < nq; i += 256) idxs_s[i] = ib[O_CSR_SUCC + q0 + i];
    }
    if (tid < 64) {
      sGB[tid] = gb[(6+l)*64 + tid];
      sef[tid] = ws[O_SEF_PREV + obase*8 + tid];
      mop[tid] = 0.f;
    } else if (tid < 128) {
      sGB[tid] = gb[(12+l)*64 + (tid-64)];
      sef[tid] = ws[O_SEF_SUCC + obase*8 + (tid-64)];
    } else if (tid < 192) {
      sef[tid] = ws[O_SEF_SERVE + obase*8 + (tid-128)];
    }
    {
      // vserve partials: 64 cols x 4 k-chunks, fully parallel
      const int col = tid & 63, j = tid >> 6;
      const float* mt = ws + O_MEANTASK + l*64;
      float acc = (j == 0) ? gb[(24+l)*64 + col] : 0.f;
#pragma unroll
      for (int kk = 0; kk < 16; ++kk) {
        const int k = j*16 + kk;
        acc = fmaf(mt[k]*(1.f/64.f), gWserve[k*64 + col], acc);
      }
      vp[j*64 + col] = acc;
    }
    __syncthreads();

    // --- phase 1: per-wave gather + matmul (no barriers) ---
    const int w = tid >> 6, lane = tid & 63;
    const int bp0 = rpp_s[0], bq0 = rps_s[0];
#pragma unroll
    for (int oo = 0; oo < 2; ++oo) {
      const int o = 2*w + oo;
      {
        int pb = min(rpp_s[o]   - bp0, CAP_P);
        int pe = min(rpp_s[o+1] - bp0, CAP_P);
        float s0 = 0.f, s1 = 0.f, s2 = 0.f, s3 = 0.f;
        int p = pb;
        for (; p + 3 < pe; p += 4) {
          const int i0 = idxp_s[p], i1 = idxp_s[p+1], i2 = idxp_s[p+2], i3 = idxp_s[p+3];
          s0 += op_in[(size_t)i0*64 + lane];
          s1 += op_in[(size_t)i1*64 + lane];
          s2 += op_in[(size_t)i2*64 + lane];
          s3 += op_in[(size_t)i3*64 + lane];
        }
        for (; p < pe; ++p) s0 += op_in[(size_t)idxp_s[p]*64 + lane];
        sums_p[o*68 + lane] = (s0 + s1) + (s2 + s3);
      }
      {
        int pb = min(rps_s[o]   - bq0, CAP_P);
        int pe = min(rps_s[o+1] - bq0, CAP_P);
        float s0 = 0.f, s1 = 0.f, s2 = 0.f, s3 = 0.f;
        int p = pb;
        for (; p + 3 < pe; p += 4) {
          const int i0 = idxs_s[p], i1 = idxs_s[p+1], i2 = idxs_s[p+2], i3 = idxs_s[p+3];
          s0 += op_in[(size_t)i0*64 + lane];
          s1 += op_in[(size_t)i1*64 + lane];
          s2 += op_in[(size_t)i2*64 + lane];
          s3 += op_in[(size_t)i3*64 + lane];
        }
        for (; p < pe; ++p) s0 += op_in[(size_t)idxs_s[p]*64 + lane];
        sums_s[o*68 + lane] = (s0 + s1) + (s2 + s3);
      }
    }

    // matmul: lane -> (op = 2w + lane>>5, cols c,c+1)
    const int oL = 2*w + (lane >> 5);
    const int d  = obase + oL;
    const int c  = (lane & 31)*2;
    float up0 = 0.f, up1 = 0.f, us0 = 0.f, us1 = 0.f;
    const int cp = rpp_s[oL+1] - rpp_s[oL];
    if (cp > 0) {
      float a0 = 0.f, a1 = 0.f;
      for (int k = 0; k < 64; ++k) {
        const float sk = sums_p[oL*68 + k];
        const float2 wv = *(const float2*)&sWp[k*64 + c];
        a0 = fmaf(sk, wv.x, a0);
        a1 = fmaf(sk, wv.y, a1);
      }
#pragma unroll
      for (int cc = 0; cc < 8; ++cc) {
        const float ev = sef[oL*8 + cc];
        const float2 wv = *(const float2*)&sWp[4096 + cc*64 + c];
        a0 = fmaf(ev, wv.x, a0);
        a1 = fmaf(ev, wv.y, a1);
      }
      const float r = 1.f/(float)cp;
      up0 = fmaf(a0, r, sGB[c]);
      up1 = fmaf(a1, r, sGB[c+1]);
    }
    const int cs = rps_s[oL+1] - rps_s[oL];
    if (cs > 0) {
      float a0 = 0.f, a1 = 0.f;
      for (int k = 0; k < 64; ++k) {
        const float sk = sums_s[oL*68 + k];
        const float2 wv = *(const float2*)&sWs[k*64 + c];
        a0 = fmaf(sk, wv.x, a0);
        a1 = fmaf(sk, wv.y, a1);
      }
#pragma unroll
      for (int cc = 0; cc < 8; ++cc) {
        const float ev = sef[64 + oL*8 + cc];
        const float2 wv = *(const float2*)&sWs[4096 + cc*64 + c];
        a0 = fmaf(ev, wv.x, a0);
        a1 = fmaf(ev, wv.y, a1);
      }
      const float r = 1.f/(float)cs;
      us0 = fmaf(a0, r, sGB[64 + c]);
      us1 = fmaf(a1, r, sGB[64 + c + 1]);
    }
    // serve term
    float g0, g1;
    {
      const float2 v0 = *(const float2*)&vp[c];
      const float2 v1 = *(const float2*)&vp[64 + c];
      const float2 v2 = *(const float2*)&vp[128 + c];
      const float2 v3 = *(const float2*)&vp[192 + c];
      g0 = (v0.x + v1.x) + (v2.x + v3.x);
      g1 = (v0.y + v1.y) + (v2.y + v3.y);
#pragma unroll
      for (int cc = 0; cc < 8; ++cc) {
        const float ev = sef[128 + oL*8 + cc] * (1.f/64.f);
        const float2 wv = *(const float2*)&sWeS[cc*64 + c];
        g0 = fmaf(ev, wv.x, g0);
        g1 = fmaf(ev, wv.y, g1);
      }
    }
    const float2 x = *(const float2*)&op_in[(size_t)d*64 + c];
    float r0 = elu1(x.x + (up0 + us0 + g0)*(1.f/3.f));
    float r1 = elu1(x.y + (up1 + us1 + g1)*(1.f/3.f));
    float2 xo; xo.x = r0; xo.y = r1;
    *(float2*)&op_out[(size_t)d*64 + c] = xo;
    if (l < 5) {
      atomicAdd(&mop[c],   r0);
      atomicAdd(&mop[c+1], r1);
      __syncthreads();
      if (tid < 64) atomicAdd(&ws[O_MEANOP + (l+1)*64 + tid], mop[tid]);
    }
  } else {
    // ---------------- task update: 16 tasks ----------------
    const int tbase = (bid - NOPB)*16;
    float* sTask  = smem;           // 4096 (all 64 tasks)
    float* sW0    = smem + 4096;    // 4608 link (node + edge)
    float* sWe3   = smem + 8704;    // 512 place edge-W
    float* vpl    = smem + 9216;    // 4x64 vplace partials
    float* sums_l = smem + 9472;    // 16 x 68
    float* sGB0   = smem + 10560;   // 64
    float* sefl   = smem + 10624;   // 128
    float* sefpl  = smem + 10752;   // 128
    float* mtp    = smem + 10880;   // 64
    int* idxl_s   = (int*)(smem + 10944);            // CAP_L
    int* rpl_s    = (int*)(smem + 10944 + CAP_L);    // 17

    const float* gWlink  = gW + (size_t)(l*72)*64;
    const float* gWplace = gW + (size_t)((18 + l)*72)*64;

    for (int i = tid*4; i < 4096; i += 1024)
      *(float4*)&sTask[i] = *(const float4*)&task_in[i];
    for (int i = tid*4; i < 4608; i += 1024)
      *(float4*)&sW0[i] = *(const float4*)&gWlink[i];
    for (int i = tid*4; i < 512; i += 1024)
      *(float4*)&sWe3[i] = *(const float4*)&gWplace[4096 + i];
    if (tid < 17) rpl_s[tid] = ib[O_RP_LINK + tbase + tid];
    {
      const int p0 = ib[O_RP_LINK + tbase];
      const int np = min(ib[O_RP_LINK + tbase + 16] - p0, CAP_L);
      for (int i = tid; i < np; i += 256) idxl_s[i] = ib[O_CSR_LINK + p0 + i];
    }
    if (tid < 64) { sGB0[tid] = gb[l*64 + tid]; mtp[tid] = 0.f; }
    if (tid < 128) sefl[tid] = ws[O_SEF_LINK + tbase*8 + tid];
    else sefpl[tid - 128] = ws[O_SEF_PLACE + tbase*8 + (tid - 128)];
    {
      const int col = tid & 63, j = tid >> 6;
      const float* mo = ws + O_MEANOP + l*64;
      float acc = (j == 0) ? gb[(18+l)*64 + col] : 0.f;
#pragma unroll
      for (int kk = 0; kk < 16; ++kk) {
        const int k = j*16 + kk;
        acc = fmaf(mo[k]*(1.f/4096.f), gWplace[k*64 + col], acc);
      }
      vpl[j*64 + col] = acc;
    }
    __syncthreads();

    const int w = tid >> 6, lane = tid & 63;
    const int b0 = rpl_s[0];
#pragma unroll
    for (int tt = 0; tt < 4; ++tt) {
      const int t = 4*w + tt;
      int pb = min(rpl_s[t]   - b0, CAP_L);
      int pe = min(rpl_s[t+1] - b0, CAP_L);
      float s0 = 0.f, s1 = 0.f, s2 = 0.f, s3 = 0.f;
      int p = pb;
      for (; p + 3 < pe; p += 4) {
        const int i0 = idxl_s[p], i1 = idxl_s[p+1], i2 = idxl_s[p+2], i3 = idxl_s[p+3];
        s0 += sTask[i0*64 + lane];
        s1 += sTask[i1*64 + lane];
        s2 += sTask[i2*64 + lane];
        s3 += sTask[i3*64 + lane];
      }
      for (; p < pe; ++p) s0 += sTask[idxl_s[p]*64 + lane];
      sums_l[t*68 + lane] = (s0 + s1) + (s2 + s3);
    }

    // matmul: lane -> (task = 4w + lane>>4, cols c..c+3)
    const int tL = 4*w + (lane >> 4);
    const int tG = tbase + tL;
    const int c  = (lane & 15)*4;
    float4 ul = make_float4(0.f,0.f,0.f,0.f);
    const int cl2 = rpl_s[tL+1] - rpl_s[tL];
    if (cl2 > 0) {
      float4 a = make_float4(0.f,0.f,0.f,0.f);
      for (int k = 0; k < 64; ++k)
        fma4(a, sums_l[tL*68 + k], *(const float4*)&sW0[k*64 + c]);
#pragma unroll
      for (int cc = 0; cc < 8; ++cc)
        fma4(a, sefl[tL*8 + cc], *(const float4*)&sW0[4096 + cc*64 + c]);
      const float r = 1.f/(float)cl2;
      ul.x = fmaf(a.x, r, sGB0[c+0]);
      ul.y = fmaf(a.y, r, sGB0[c+1]);
      ul.z = fmaf(a.z, r, sGB0[c+2]);
      ul.w = fmaf(a.w, r, sGB0[c+3]);
    }
    float4 uq;
    {
      const float4 v0 = *(const float4*)&vpl[c];
      const float4 v1 = *(const float4*)&vpl[64 + c];
      const float4 v2 = *(const float4*)&vpl[128 + c];
      const float4 v3 = *(const float4*)&vpl[192 + c];
      uq.x = (v0.x + v1.x) + (v2.x + v3.x);
      uq.y = (v0.y + v1.y) + (v2.y + v3.y);
      uq.z = (v0.z + v1.z) + (v2.z + v3.z);
      uq.w = (v0.w + v1.w) + (v2.w + v3.w);
#pragma unroll
      for (int cc = 0; cc < 8; ++cc)
        fma4(uq, sefpl[tL*8 + cc]*(1.f/4096.f), *(const float4*)&sWe3[cc*64 + c]);
    }
    float4 x = *(const float4*)&sTask[tG*64 + c];
    x.x = elu1(x.x + (ul.x + uq.x)*0.5f);
    x.y = elu1(x.y + (ul.y + uq.y)*0.5f);
    x.z = elu1(x.z + (ul.z + uq.z)*0.5f);
    x.w = elu1(x.w + (ul.w + uq.w)*0.5f);
    *(float4*)&task_out[(size_t)tG*64 + c] = x;
    if (l < 5) {
      atomicAdd(&mtp[c+0], x.x);
      atomicAdd(&mtp[c+1], x.y);
      atomicAdd(&mtp[c+2], x.z);
      atomicAdd(&mtp[c+3], x.w);
      __syncthreads();
      if (tid < 64) atomicAdd(&ws[O_MEANTASK + (l+1)*64 + tid], mtp[tid]);
    }
  }
}

// ------------- final head: out[i,t] = a_i + b_e + c_t + bias -------------
__global__ __launch_bounds__(256) void k_final(
    const float* __restrict__ opF, const float* __restrict__ taskF,
    const float* __restrict__ finalW, const float* __restrict__ finalb,
    const float* __restrict__ bplace, float* __restrict__ out)
{
  __shared__ float sTask[4096];
  __shared__ float cvec[64];
  const int tid = threadIdx.x;
  for (int i = tid*4; i < 4096; i += 1024)
    *(float4*)&sTask[i] = *(const float4*)&taskF[i];
  __syncthreads();
  const int lane = tid & 63;
  const int wave = tid >> 6;
  const float w2 = finalW[72 + lane];
  for (int jt = 0; jt < 16; ++jt) {
    const int t = wave*16 + jt;
    float v = sTask[t*64 + lane]*w2;
    for (int m = 32; m >= 1; m >>= 1) v += __shfl_xor(v, m, 64);
    if (lane == 0) cvec[t] = v;
  }
  __syncthreads();
  const int e = blockIdx.x*256 + tid;
  float v = opF[e]*finalW[lane];
  for (int m = 32; m >= 1; m >>= 1) v += __shfl_xor(v, m, 64);
  out[e] = v + bplace[e] + cvec[lane] + finalb[0];
}

extern "C" void kernel_launch(void* const* d_in, const int* in_sizes, int n_in,
                              void* d_out, int out_size, void* d_ws, size_t ws_size,
                              hipStream_t stream)
{
  (void)in_sizes; (void)n_in; (void)out_size;
  if (ws_size < (size_t)O_TOTAL * sizeof(float)) return;

  const float* op_feats     = (const float*)d_in[0];
  const float* task_feats   = (const float*)d_in[1];
  const float* tensor_feats = (const float*)d_in[2];
  const float* link_feats   = (const float*)d_in[3];
  const float* place_feats  = (const float*)d_in[4];
  const int*   prev_src     = (const int*)d_in[5];
  const int*   prev_dst     = (const int*)d_in[6];
  const int*   link_src     = (const int*)d_in[7];
  const int*   link_dst     = (const int*)d_in[8];
  const float* op_W         = (const float*)d_in[9];
  const float* op_b         = (const float*)d_in[10];
  const float* task_W       = (const float*)d_in[11];
  const float* task_b       = (const float*)d_in[12];
  const float* eW           = (const float*)d_in[13];
  const float* eb           = (const float*)d_in[14];
  const float* gW           = (const float*)d_in[15];
  const float* gb           = (const float*)d_in[16];
  const float* finalW       = (const float*)d_in[17];
  const float* finalb       = (const float*)d_in[18];
  float* w = (float*)d_ws;
  float* out = (float*)d_out;

  hipMemsetAsync(d_ws, 0, (size_t)O_ZERO_END * sizeof(float), stream);

  k_op_embed<<<256, 256, 0, stream>>>(op_feats, op_W, op_b, w + O_OP_A, w + O_MEANOP);
  k_task_embed<<<1, 256, 0, stream>>>(task_feats, task_W, task_b, w + O_TASK_A, w + O_MEANTASK);
  k_edge_pass1<<<128, 256, 0, stream>>>(tensor_feats, link_feats, prev_src, prev_dst,
                                        link_src, link_dst, eW, eb, w);
  k_scan<<<1, 1024, 0, stream>>>(w);
  k_fill<<<128, 256, 0, stream>>>(prev_src, prev_dst, link_src, link_dst, w);
  k_place<<<256, 256, 0, stream>>>(place_feats, eW, eb, finalW, w);

  for (int l = 0; l < 6; ++l) {
    const float* oin  = w + ((l & 1) ? O_OP_B : O_OP_A);
    float*       oout = w + ((l & 1) ? O_OP_A : O_OP_B);
    const float* tin  = w + ((l & 1) ? O_TASK_B : O_TASK_A);
    float*       tout = w + ((l & 1) ? O_TASK_A : O_TASK_B);
    k_layer<<<NOPB + 4, 256, 0, stream>>>(l, gW, gb, oin, oout, tin, tout, w);
  }

  k_final<<<1024, 256, 0, stream>>>(w + O_OP_A, w + O_TASK_A, finalW, finalb,
                                    w + O_BPLACE, out);
}

// Round 3
// 262.322 us; speedup vs baseline: 1.6710x; 1.0558x over previous
//
#include <hip/hip_runtime.h>
#include <math.h>

#define NOP 4096
#define NTASK 64
#define NTENSOR 32768
#define NLINK 1024
#define NPLACE (NOP*NTASK)
#define CAP 64
#define NOPB 512          // op-update blocks (8 ops each)

// ---- workspace layout (units of 4 bytes); ws is 256 MiB ----
enum : int {
  O_CNT_PREV  = 0,                          // 4096 ints
  O_CNT_SUCC  = O_CNT_PREV + NOP,
  O_CNT_LINK  = O_CNT_SUCC + NOP,           // 64
  O_SEF_PREV  = O_CNT_LINK + 64,            // NOP*8
  O_SEF_SUCC  = O_SEF_PREV + NOP*8,
  O_SEF_LINK  = O_SEF_SUCC + NOP*8,         // 64*8
  O_SEF_PLACE = O_SEF_LINK + 64*8,          // 64*8
  O_SEF_SERVE = O_SEF_PLACE + 64*8,         // NOP*8
  O_OP_A      = O_SEF_SERVE + NOP*8,        // NOP*64
  O_OP_B      = O_OP_A + NOP*64,
  O_TASK_A    = O_OP_B + NOP*64,            // 64*64
  O_TASK_B    = O_TASK_A + 64*64,
  O_BPLACE    = O_TASK_B + 64*64,           // NPLACE
  O_MOPP      = O_BPLACE + NPLACE,          // 2 * 512*64 (per-parity op-sum partials)
  O_MTPP      = O_MOPP + 2*512*64,          // 2 * 4*64
  O_SPLP      = O_MTPP + 2*4*64,            // 256*512 place-ef partials
  O_CSRP_PREV = O_SPLP + 256*512,           // NOP*CAP ints (src per slot)
  O_CSRP_SUCC = O_CSRP_PREV + NOP*CAP,
  O_CSRP_LINK = O_CSRP_SUCC + NOP*CAP,      // 64*CAP
  O_EFS_PREV  = O_CSRP_LINK + 64*CAP,       // NOP*CAP*8 floats
  O_EFS_SUCC  = O_EFS_PREV + NOP*CAP*8,
  O_EFS_LINK  = O_EFS_SUCC + NOP*CAP*8,     // 64*CAP*8
  O_TOTAL     = O_EFS_LINK + 64*CAP*8
};

__device__ __forceinline__ float elu1(float x) { return x > 0.f ? x : expm1f(x); }

__device__ __forceinline__ void fma4(float4& a, const float s, const float4 w) {
  a.x = fmaf(s, w.x, a.x);
  a.y = fmaf(s, w.y, a.y);
  a.z = fmaf(s, w.z, a.z);
  a.w = fmaf(s, w.w, a.w);
}

// ---------------- op embedding: [4096,256]@[256,64] + elu ----------------
__global__ __launch_bounds__(256) void k_op_embed(
    const float* __restrict__ A, const float* __restrict__ W, const float* __restrict__ b,
    float* __restrict__ out, float* __restrict__ mopp0)
{
  __shared__ float sW[8192];       // half of W (128 rows x 64)
  __shared__ float sA[16*260];     // 16 op rows, padded stride 260
  __shared__ float4 red[256];
  const int tid = threadIdx.x;
  const int obase = blockIdx.x * 16;
  for (int i = tid; i < 4096; i += 256) {
    const int o = i >> 8, k = i & 255;
    sA[o*260 + k] = A[(size_t)(obase + o)*256 + k];
  }
  const int o = tid >> 4, hq = tid & 15, h0 = hq*4;
  float4 acc = *(const float4*)&b[h0];
  for (int half = 0; half < 2; ++half) {
    __syncthreads();
    for (int i = tid*4; i < 8192; i += 1024)
      *(float4*)&sW[i] = *(const float4*)&W[half*8192 + i];
    __syncthreads();
    const float* a = &sA[o*260 + half*128];
    for (int k = 0; k < 128; ++k)
      fma4(acc, a[k], *(const float4*)&sW[k*64 + h0]);
  }
  acc.x = elu1(acc.x); acc.y = elu1(acc.y); acc.z = elu1(acc.z); acc.w = elu1(acc.w);
  *(float4*)&out[(size_t)(obase + o)*64 + h0] = acc;
  red[tid] = acc;
  __syncthreads();
  if (tid < 16) {
    float4 s = make_float4(0.f,0.f,0.f,0.f);
    for (int g = 0; g < 16; ++g) {
      float4 v = red[g*16 + tid];
      s.x += v.x; s.y += v.y; s.z += v.z; s.w += v.w;
    }
    // direct per-block partial store (parity 0, slot = blockIdx)
    *(float4*)&mopp0[blockIdx.x*64 + tid*4] = s;
  }
}

// ------- task embedding [64,64]@[64,64] + elu; ALSO zeroes the count arrays -------
__global__ __launch_bounds__(256) void k_task_embed(
    const float* __restrict__ A, const float* __restrict__ W, const float* __restrict__ b,
    float* __restrict__ out, float* __restrict__ mtpp0, float* __restrict__ ws)
{
  __shared__ float sA[64*65];
  __shared__ float sW[64*64];
  __shared__ float4 red[256];
  const int tid = threadIdx.x;
  int* ib = (int*)ws;
  for (int i = tid; i < NOP*2 + 64; i += 256) ib[O_CNT_PREV + i] = 0;
  for (int i = tid; i < 4096; i += 256) {
    const int t = i >> 6, k = i & 63;
    sA[t*65 + k] = A[i];
  }
  for (int i = tid*4; i < 4096; i += 1024)
    *(float4*)&sW[i] = *(const float4*)&W[i];
  __syncthreads();
  const int og = tid >> 4, hq = tid & 15, h0 = hq*4;
  float4 msum = make_float4(0.f,0.f,0.f,0.f);
  for (int tg = 0; tg < 4; ++tg) {
    const int t = tg*16 + og;
    float4 acc = *(const float4*)&b[h0];
    const float* a = &sA[t*65];
    for (int k = 0; k < 64; ++k)
      fma4(acc, a[k], *(const float4*)&sW[k*64 + h0]);
    acc.x = elu1(acc.x); acc.y = elu1(acc.y); acc.z = elu1(acc.z); acc.w = elu1(acc.w);
    *(float4*)&out[t*64 + h0] = acc;
    msum.x += acc.x; msum.y += acc.y; msum.z += acc.z; msum.w += acc.w;
  }
  red[tid] = msum;
  __syncthreads();
  if (tid < 16) {
    float4 s = make_float4(0.f,0.f,0.f,0.f);
    for (int g = 0; g < 16; ++g) {
      float4 v = red[g*16 + tid];
      s.x += v.x; s.y += v.y; s.z += v.z; s.w += v.w;
    }
    *(float4*)&mtpp0[tid*4] = s;   // parity 0, slot 0
  }
}

// ------- tensor + link edges: transform, padded-CSR scatter (no float atomics) -------
__global__ __launch_bounds__(256) void k_edge_pass1(
    const float* __restrict__ tensor_feats, const float* __restrict__ link_feats,
    const int* __restrict__ prev_src, const int* __restrict__ prev_dst,
    const int* __restrict__ link_src, const int* __restrict__ link_dst,
    const float* __restrict__ eW, const float* __restrict__ eb,
    float* __restrict__ ws)
{
  __shared__ float sEW[384];
  __shared__ float sEB[24];
  const int tid = threadIdx.x;
  for (int i = tid; i < 384; i += 256) sEW[i] = eW[i];
  if (tid < 24) sEB[tid] = eb[tid];
  __syncthreads();
  int* ib = (int*)ws;
  const int e = blockIdx.x*256 + tid;
  float raw[16];
  *(float4*)&raw[0]  = *(const float4*)&tensor_feats[(size_t)e*16 + 0];
  *(float4*)&raw[4]  = *(const float4*)&tensor_feats[(size_t)e*16 + 4];
  *(float4*)&raw[8]  = *(const float4*)&tensor_feats[(size_t)e*16 + 8];
  *(float4*)&raw[12] = *(const float4*)&tensor_feats[(size_t)e*16 + 12];
  float efp[8], efs[8];
#pragma unroll
  for (int c = 0; c < 8; ++c) { efp[c] = sEB[8+c]; efs[c] = sEB[16+c]; }
#pragma unroll
  for (int k = 0; k < 16; ++k) {
    const float a = raw[k];
#pragma unroll
    for (int c = 0; c < 8; ++c) {
      efp[c] = fmaf(a, sEW[128 + k*8 + c], efp[c]);
      efs[c] = fmaf(a, sEW[256 + k*8 + c], efs[c]);
    }
  }
#pragma unroll
  for (int c = 0; c < 8; ++c) { efp[c] = elu1(efp[c]); efs[c] = elu1(efs[c]); }
  const int pd = prev_dst[e], ps = prev_src[e];
  {
    int pos = atomicAdd(&ib[O_CNT_PREV + pd], 1);
    if (pos < CAP) {
      ib[O_CSRP_PREV + pd*CAP + pos] = ps;
      float* dst = ws + O_EFS_PREV + ((size_t)pd*CAP + pos)*8;
      *(float4*)&dst[0] = make_float4(efp[0],efp[1],efp[2],efp[3]);
      *(float4*)&dst[4] = make_float4(efp[4],efp[5],efp[6],efp[7]);
    }
  }
  {
    int pos = atomicAdd(&ib[O_CNT_SUCC + ps], 1);
    if (pos < CAP) {
      ib[O_CSRP_SUCC + ps*CAP + pos] = pd;
      float* dst = ws + O_EFS_SUCC + ((size_t)ps*CAP + pos)*8;
      *(float4*)&dst[0] = make_float4(efs[0],efs[1],efs[2],efs[3]);
      *(float4*)&dst[4] = make_float4(efs[4],efs[5],efs[6],efs[7]);
    }
  }
  if (e < NLINK) {
    float rl[16];
    *(float4*)&rl[0]  = *(const float4*)&link_feats[(size_t)e*16 + 0];
    *(float4*)&rl[4]  = *(const float4*)&link_feats[(size_t)e*16 + 4];
    *(float4*)&rl[8]  = *(const float4*)&link_feats[(size_t)e*16 + 8];
    *(float4*)&rl[12] = *(const float4*)&link_feats[(size_t)e*16 + 12];
    float efl[8];
#pragma unroll
    for (int c = 0; c < 8; ++c) efl[c] = sEB[c];
#pragma unroll
    for (int k = 0; k < 16; ++k) {
      const float a = rl[k];
#pragma unroll
      for (int c = 0; c < 8; ++c) efl[c] = fmaf(a, sEW[k*8 + c], efl[c]);
    }
    const int ld = link_dst[e];
    int pos = atomicAdd(&ib[O_CNT_LINK + ld], 1);
    if (pos < CAP) {
      ib[O_CSRP_LINK + ld*CAP + pos] = link_src[e];
      float* dst = ws + O_EFS_LINK + ((size_t)ld*CAP + pos)*8;
      *(float4*)&dst[0] = make_float4(elu1(efl[0]),elu1(efl[1]),elu1(efl[2]),elu1(efl[3]));
      *(float4*)&dst[4] = make_float4(elu1(efl[4]),elu1(efl[5]),elu1(efl[6]),elu1(efl[7]));
    }
  }
}

// ------------- place/serve pass: per-edge b term, serve sums, place partials -------------
__global__ __launch_bounds__(256) void k_place(
    const float* __restrict__ place_feats, const float* __restrict__ eW,
    const float* __restrict__ eb, const float* __restrict__ finalW,
    float* __restrict__ ws)
{
  __shared__ float sW3[128], sW4[128], sB3[8], sB4[8], sW1[8];
  __shared__ float pl[512];
  const int tid = threadIdx.x;
  if (tid < 128) { sW3[tid] = eW[3*128 + tid]; sW4[tid] = eW[4*128 + tid]; }
  if (tid < 8) { sB3[tid] = eb[24+tid]; sB4[tid] = eb[32+tid]; sW1[tid] = finalW[64+tid]; }
  for (int i = tid; i < 512; i += 256) pl[i] = 0.f;
  __syncthreads();
  const int lane = tid & 63;
  const int wave = (blockIdx.x*256 + tid) >> 6;   // 0..1023, 4 op-rows each
  float pacc[8];
#pragma unroll
  for (int c = 0; c < 8; ++c) pacc[c] = 0.f;
  float* bplace = ws + O_BPLACE;
  float* sserve = ws + O_SEF_SERVE;
  for (int j = 0; j < 4; ++j) {
    const int i = wave*4 + j;
    const int e = i*64 + lane;
    float raw[16];
    *(float4*)&raw[0]  = *(const float4*)&place_feats[(size_t)e*16 + 0];
    *(float4*)&raw[4]  = *(const float4*)&place_feats[(size_t)e*16 + 4];
    *(float4*)&raw[8]  = *(const float4*)&place_feats[(size_t)e*16 + 8];
    *(float4*)&raw[12] = *(const float4*)&place_feats[(size_t)e*16 + 12];
    float efp[8], efs[8];
#pragma unroll
    for (int c = 0; c < 8; ++c) { efp[c] = sB3[c]; efs[c] = sB4[c]; }
#pragma unroll
    for (int k = 0; k < 16; ++k) {
      const float a = raw[k];
#pragma unroll
      for (int c = 0; c < 8; ++c) {
        efp[c] = fmaf(a, sW3[k*8 + c], efp[c]);
        efs[c] = fmaf(a, sW4[k*8 + c], efs[c]);
      }
    }
    float bp = 0.f;
#pragma unroll
    for (int c = 0; c < 8; ++c) {
      efp[c] = elu1(efp[c]);
      efs[c] = elu1(efs[c]);
      bp = fmaf(efp[c], sW1[c], bp);
      pacc[c] += efp[c];
    }
    bplace[e] = bp;
#pragma unroll
    for (int c = 0; c < 8; ++c) {
      float v = efs[c];
      for (int m = 32; m >= 1; m >>= 1) v += __shfl_xor(v, m, 64);
      if (lane == 0) sserve[i*8 + c] = v;
    }
  }
#pragma unroll
  for (int c = 0; c < 8; ++c) atomicAdd(&pl[lane*8 + c], pacc[c]);
  __syncthreads();
  // per-block partial store (no global atomics)
  for (int i = tid; i < 512; i += 256) ws[O_SPLP + blockIdx.x*512 + i] = pl[i];
}

// ------------- SEF sums from padded slots + SPL partial reduce -------------
__global__ __launch_bounds__(256) void k_sef(float* __restrict__ ws)
{
  const int b = blockIdx.x, tid = threadIdx.x;
  const int* ib = (const int*)ws;
  if (b < 256) {
    const bool isP = (b < 128);
    const int bb = isP ? b : b - 128;
    const int d = bb*32 + (tid >> 3), c = tid & 7;
    const int cnt = min(ib[(isP ? O_CNT_PREV : O_CNT_SUCC) + d], CAP);
    const float* efs = ws + (isP ? O_EFS_PREV : O_EFS_SUCC) + (size_t)d*CAP*8;
    float s0 = 0.f, s1 = 0.f;
    int j = 0;
    for (; j + 1 < cnt; j += 2) { s0 += efs[j*8 + c]; s1 += efs[j*8 + 8 + c]; }
    if (j < cnt) s0 += efs[j*8 + c];
    ws[(isP ? O_SEF_PREV : O_SEF_SUCC) + d*8 + c] = s0 + s1;
  } else if (b == 256) {
    for (int rep = 0; rep < 2; ++rep) {
      const int idx = rep*256 + tid;
      const int d = idx >> 3, c = idx & 7;
      const int cnt = min(ib[O_CNT_LINK + d], CAP);
      const float* efs = ws + O_EFS_LINK + (size_t)d*CAP*8;
      float s0 = 0.f, s1 = 0.f;
      int j = 0;
      for (; j + 1 < cnt; j += 2) { s0 += efs[j*8 + c]; s1 += efs[j*8 + 8 + c]; }
      if (j < cnt) s0 += efs[j*8 + c];
      ws[O_SEF_LINK + d*8 + c] = s0 + s1;
    }
  } else {
    // reduce 256 place partials -> SEF_PLACE[512]
    float s0 = 0.f, s1 = 0.f;
    for (int r = 0; r < 256; ++r) {
      const float2 v = *(const float2*)&ws[O_SPLP + r*512 + tid*2];
      s0 += v.x; s1 += v.y;
    }
    ws[O_SEF_PLACE + tid*2]     = s0;
    ws[O_SEF_PLACE + tid*2 + 1] = s1;
  }
}

// ------------- one GNN layer -------------
// blocks 0..NOPB-1: 8 ops each; blocks NOPB..NOPB+3: 16 tasks each.
__global__ __launch_bounds__(256) void k_layer(
    const int l,
    const float* __restrict__ gW, const float* __restrict__ gb,
    const float* __restrict__ op_in, float* __restrict__ op_out,
    const float* __restrict__ task_in, float* __restrict__ task_out,
    float* __restrict__ ws)
{
  __shared__ float smem[12544];
  const int tid = threadIdx.x;
  const int bid = blockIdx.x;
  const int* ib = (const int*)ws;
  const int rpar = l & 1, wpar = (l + 1) & 1;

  if (bid < NOPB) {
    // ---------------- op update: 8 ops ----------------
    float* sWp  = smem;             // 4608 (node 4096 + edge 512) prev
    float* sWs  = smem + 4608;      // 4608 succ
    float* sWeS = smem + 9216;      // 512 serve edge-W
    float* vp   = smem + 9728;      // 4x64 vserve partials
    float* sums_p = smem + 9984;    // 8 x 68
    float* sums_s = smem + 10528;   // 8 x 68
    float* sGB  = smem + 11072;     // 128 (prev bias, succ bias)
    float* sef  = smem + 11200;     // 192 (prev 64, succ 64, serve 64)
    float* mop  = smem + 11392;     // 64
    int* idxp_s = (int*)(smem + 11456);  // 8*CAP
    int* idxs_s = (int*)(smem + 11968);  // 8*CAP
    int* cp_s   = (int*)(smem + 12480);  // 8 (real counts)
    int* cs_s   = (int*)(smem + 12488);  // 8

    const int obase = bid*8;
    const float* gWprev  = gW + (size_t)((6  + l)*72)*64;
    const float* gWsucc  = gW + (size_t)((12 + l)*72)*64;
    const float* gWserve = gW + (size_t)((24 + l)*72)*64;

    // --- staging (one barrier) ---
    for (int i = tid*4; i < 4608; i += 1024) {
      *(float4*)&sWp[i] = *(const float4*)&gWprev[i];
      *(float4*)&sWs[i] = *(const float4*)&gWsucc[i];
    }
    for (int i = tid*4; i < 512; i += 1024)
      *(float4*)&sWeS[i] = *(const float4*)&gWserve[4096 + i];
    if (tid < 8) {
      cp_s[tid] = ib[O_CNT_PREV + obase + tid];
      cs_s[tid] = ib[O_CNT_SUCC + obase + tid];
    }
    for (int i = tid; i < 8*CAP; i += 256) {
      const int o = i >> 6, j = i & (CAP-1);
      if (j < ib[O_CNT_PREV + obase + o]) idxp_s[i] = ib[O_CSRP_PREV + (obase+o)*CAP + j];
      if (j < ib[O_CNT_SUCC + obase + o]) idxs_s[i] = ib[O_CSRP_SUCC + (obase+o)*CAP + j];
    }
    if (tid < 64) {
      sGB[tid] = gb[(6+l)*64 + tid];
      sef[tid] = ws[O_SEF_PREV + obase*8 + tid];
      mop[tid] = 0.f;
    } else if (tid < 128) {
      sGB[tid] = gb[(12+l)*64 + (tid-64)];
      sef[tid] = ws[O_SEF_SUCC + obase*8 + (tid-64)];
    } else if (tid < 192) {
      sef[tid] = ws[O_SEF_SERVE + obase*8 + (tid-128)];
    }
    {
      // vserve partials from task-sum partials (<=4 slots)
      const int col = tid & 63, j = tid >> 6;
      const float* mtpp = ws + O_MTPP + rpar*256;
      const int nst = (l == 0) ? 1 : 4;
      float acc = (j == 0) ? gb[(24+l)*64 + col] : 0.f;
#pragma unroll
      for (int kk = 0; kk < 16; ++kk) {
        const int k = j*16 + kk;
        float mt = 0.f;
        for (int s = 0; s < nst; ++s) mt += mtpp[s*64 + k];
        acc = fmaf(mt*(1.f/64.f), gWserve[k*64 + col], acc);
      }
      vp[j*64 + col] = acc;
    }
    __syncthreads();

    // --- per-wave gather ---
    const int w = tid >> 6, lane = tid & 63;
#pragma unroll
    for (int oo = 0; oo < 2; ++oo) {
      const int o = 2*w + oo;
      {
        const int pe = min(cp_s[o], CAP);
        float s0 = 0.f, s1 = 0.f, s2 = 0.f, s3 = 0.f;
        int p = 0;
        for (; p + 3 < pe; p += 4) {
          const int i0 = idxp_s[o*CAP+p], i1 = idxp_s[o*CAP+p+1],
                    i2 = idxp_s[o*CAP+p+2], i3 = idxp_s[o*CAP+p+3];
          s0 += op_in[(size_t)i0*64 + lane];
          s1 += op_in[(size_t)i1*64 + lane];
          s2 += op_in[(size_t)i2*64 + lane];
          s3 += op_in[(size_t)i3*64 + lane];
        }
        for (; p < pe; ++p) s0 += op_in[(size_t)idxp_s[o*CAP+p]*64 + lane];
        sums_p[o*68 + lane] = (s0 + s1) + (s2 + s3);
      }
      {
        const int pe = min(cs_s[o], CAP);
        float s0 = 0.f, s1 = 0.f, s2 = 0.f, s3 = 0.f;
        int p = 0;
        for (; p + 3 < pe; p += 4) {
          const int i0 = idxs_s[o*CAP+p], i1 = idxs_s[o*CAP+p+1],
                    i2 = idxs_s[o*CAP+p+2], i3 = idxs_s[o*CAP+p+3];
          s0 += op_in[(size_t)i0*64 + lane];
          s1 += op_in[(size_t)i1*64 + lane];
          s2 += op_in[(size_t)i2*64 + lane];
          s3 += op_in[(size_t)i3*64 + lane];
        }
        for (; p < pe; ++p) s0 += op_in[(size_t)idxs_s[o*CAP+p]*64 + lane];
        sums_s[o*68 + lane] = (s0 + s1) + (s2 + s3);
      }
    }

    // --- matmul: lane -> (op = 2w + lane>>5, cols c,c+1) ---
    const int oL = 2*w + (lane >> 5);
    const int d  = obase + oL;
    const int c  = (lane & 31)*2;
    float up0 = 0.f, up1 = 0.f, us0 = 0.f, us1 = 0.f;
    const int cp = cp_s[oL];
    if (cp > 0) {
      float a0 = 0.f, a1 = 0.f;
      for (int k = 0; k < 64; ++k) {
        const float sk = sums_p[oL*68 + k];
        const float2 wv = *(const float2*)&sWp[k*64 + c];
        a0 = fmaf(sk, wv.x, a0);
        a1 = fmaf(sk, wv.y, a1);
      }
#pragma unroll
      for (int cc = 0; cc < 8; ++cc) {
        const float ev = sef[oL*8 + cc];
        const float2 wv = *(const float2*)&sWp[4096 + cc*64 + c];
        a0 = fmaf(ev, wv.x, a0);
        a1 = fmaf(ev, wv.y, a1);
      }
      const float r = 1.f/(float)cp;
      up0 = fmaf(a0, r, sGB[c]);
      up1 = fmaf(a1, r, sGB[c+1]);
    }
    const int cs = cs_s[oL];
    if (cs > 0) {
      float a0 = 0.f, a1 = 0.f;
      for (int k = 0; k < 64; ++k) {
        const float sk = sums_s[oL*68 + k];
        const float2 wv = *(const float2*)&sWs[k*64 + c];
        a0 = fmaf(sk, wv.x, a0);
        a1 = fmaf(sk, wv.y, a1);
      }
#pragma unroll
      for (int cc = 0; cc < 8; ++cc) {
        const float ev = sef[64 + oL*8 + cc];
        const float2 wv = *(const float2*)&sWs[4096 + cc*64 + c];
        a0 = fmaf(ev, wv.x, a0);
        a1 = fmaf(ev, wv.y, a1);
      }
      const float r = 1.f/(float)cs;
      us0 = fmaf(a0, r, sGB[64 + c]);
      us1 = fmaf(a1, r, sGB[64 + c + 1]);
    }
    float g0, g1;
    {
      const float2 v0 = *(const float2*)&vp[c];
      const float2 v1 = *(const float2*)&vp[64 + c];
      const float2 v2 = *(const float2*)&vp[128 + c];
      const float2 v3 = *(const float2*)&vp[192 + c];
      g0 = (v0.x + v1.x) + (v2.x + v3.x);
      g1 = (v0.y + v1.y) + (v2.y + v3.y);
#pragma unroll
      for (int cc = 0; cc < 8; ++cc) {
        const float ev = sef[128 + oL*8 + cc] * (1.f/64.f);
        const float2 wv = *(const float2*)&sWeS[cc*64 + c];
        g0 = fmaf(ev, wv.x, g0);
        g1 = fmaf(ev, wv.y, g1);
      }
    }
    const float2 x = *(const float2*)&op_in[(size_t)d*64 + c];
    const float r0 = elu1(x.x + (up0 + us0 + g0)*(1.f/3.f));
    const float r1 = elu1(x.y + (up1 + us1 + g1)*(1.f/3.f));
    float2 xo; xo.x = r0; xo.y = r1;
    *(float2*)&op_out[(size_t)d*64 + c] = xo;
    // block partial of op-sum (for next layer's means)
    atomicAdd(&mop[c],   r0);
    atomicAdd(&mop[c+1], r1);
    __syncthreads();
    if (tid < 64) ws[O_MOPP + wpar*32768 + bid*64 + tid] = mop[tid];
  } else {
    // ---------------- task update: 16 tasks ----------------
    const int tbase = (bid - NOPB)*16;
    float* sTask  = smem;           // 4096 (all 64 tasks)
    float* sW0    = smem + 4096;    // 4608 link (node + edge)
    float* sWe3   = smem + 8704;    // 512 place edge-W
    float* vpl    = smem + 9216;    // 4x64 vplace partials
    float* mo4    = smem + 9472;    // 4x64 op-mean partials
    float* sums_l = smem + 9728;    // 16 x 68
    float* sGB0   = smem + 10816;   // 64
    float* sefl   = smem + 10880;   // 128
    float* sefpl  = smem + 11008;   // 128
    float* mtp    = smem + 11136;   // 64
    int* idxl_s   = (int*)(smem + 11200);  // 16*CAP
    int* cl_s     = (int*)(smem + 12224);  // 16

    const float* gWlink  = gW + (size_t)(l*72)*64;
    const float* gWplace = gW + (size_t)((18 + l)*72)*64;

    for (int i = tid*4; i < 4096; i += 1024)
      *(float4*)&sTask[i] = *(const float4*)&task_in[i];
    for (int i = tid*4; i < 4608; i += 1024)
      *(float4*)&sW0[i] = *(const float4*)&gWlink[i];
    for (int i = tid*4; i < 512; i += 1024)
      *(float4*)&sWe3[i] = *(const float4*)&gWplace[4096 + i];
    if (tid < 16) cl_s[tid] = ib[O_CNT_LINK + tbase + tid];
    for (int i = tid; i < 16*CAP; i += 256) {
      const int t = i >> 6, j = i & (CAP-1);
      if (j < ib[O_CNT_LINK + tbase + t]) idxl_s[i] = ib[O_CSRP_LINK + (tbase+t)*CAP + j];
    }
    if (tid < 64) { sGB0[tid] = gb[l*64 + tid]; mtp[tid] = 0.f; }
    if (tid < 128) sefl[tid] = ws[O_SEF_LINK + tbase*8 + tid];
    else if (tid < 256) sefpl[tid - 128] = ws[O_SEF_PLACE + tbase*8 + (tid - 128)];
    {
      // reduce op-sum partials -> mo4
      const int col = tid & 63, g = tid >> 6;
      const float* mopp = ws + O_MOPP + rpar*32768;
      const int nso = (l == 0) ? 256 : 512;
      float s0 = 0.f, s1 = 0.f;
      int sI = g;
      for (; sI + 4 < nso; sI += 8) { s0 += mopp[sI*64 + col]; s1 += mopp[(sI+4)*64 + col]; }
      for (; sI < nso; sI += 4) s0 += mopp[sI*64 + col];
      mo4[g*64 + col] = s0 + s1;
    }
    __syncthreads();
    {
      // vplace partials from mo4
      const int col = tid & 63, g = tid >> 6;
      float acc = (g == 0) ? gb[(18+l)*64 + col] : 0.f;
#pragma unroll
      for (int kk = 0; kk < 16; ++kk) {
        const int k = g*16 + kk;
        const float mok = (mo4[k] + mo4[64+k]) + (mo4[128+k] + mo4[192+k]);
        acc = fmaf(mok*(1.f/4096.f), gWplace[k*64 + col], acc);
      }
      vpl[g*64 + col] = acc;
    }
    __syncthreads();

    const int w = tid >> 6, lane = tid & 63;
#pragma unroll
    for (int tt = 0; tt < 4; ++tt) {
      const int t = 4*w + tt;
      const int pe = min(cl_s[t], CAP);
      float s0 = 0.f, s1 = 0.f, s2 = 0.f, s3 = 0.f;
      int p = 0;
      for (; p + 3 < pe; p += 4) {
        const int i0 = idxl_s[t*CAP+p], i1 = idxl_s[t*CAP+p+1],
                  i2 = idxl_s[t*CAP+p+2], i3 = idxl_s[t*CAP+p+3];
        s0 += sTask[i0*64 + lane];
        s1 += sTask[i1*64 + lane];
        s2 += sTask[i2*64 + lane];
        s3 += sTask[i3*64 + lane];
      }
      for (; p < pe; ++p) s0 += sTask[idxl_s[t*CAP+p]*64 + lane];
      sums_l[t*68 + lane] = (s0 + s1) + (s2 + s3);
    }

    const int tL = 4*w + (lane >> 4);
    const int tG = tbase + tL;
    const int c  = (lane & 15)*4;
    float4 ul = make_float4(0.f,0.f,0.f,0.f);
    const int cl2 = cl_s[tL];
    if (cl2 > 0) {
      float4 a = make_float4(0.f,0.f,0.f,0.f);
      for (int k = 0; k < 64; ++k)
        fma4(a, sums_l[tL*68 + k], *(const float4*)&sW0[k*64 + c]);
#pragma unroll
      for (int cc = 0; cc < 8; ++cc)
        fma4(a, sefl[tL*8 + cc], *(const float4*)&sW0[4096 + cc*64 + c]);
      const float r = 1.f/(float)cl2;
      ul.x = fmaf(a.x, r, sGB0[c+0]);
      ul.y = fmaf(a.y, r, sGB0[c+1]);
      ul.z = fmaf(a.z, r, sGB0[c+2]);
      ul.w = fmaf(a.w, r, sGB0[c+3]);
    }
    float4 uq;
    {
      const float4 v0 = *(const float4*)&vpl[c];
      const float4 v1 = *(const float4*)&vpl[64 + c];
      const float4 v2 = *(const float4*)&vpl[128 + c];
      const float4 v3 = *(const float4*)&vpl[192 + c];
      uq.x = (v0.x + v1.x) + (v2.x + v3.x);
      uq.y = (v0.y + v1.y) + (v2.y + v3.y);
      uq.z = (v0.z + v1.z) + (v2.z + v3.z);
      uq.w = (v0.w + v1.w) + (v2.w + v3.w);
#pragma unroll
      for (int cc = 0; cc < 8; ++cc)
        fma4(uq, sefpl[tL*8 + cc]*(1.f/4096.f), *(const float4*)&sWe3[cc*64 + c]);
    }
    float4 x = *(const float4*)&sTask[tG*64 + c];
    x.x = elu1(x.x + (ul.x + uq.x)*0.5f);
    x.y = elu1(x.y + (ul.y + uq.y)*0.5f);
    x.z = elu1(x.z + (ul.z + uq.z)*0.5f);
    x.w = elu1(x.w + (ul.w + uq.w)*0.5f);
    *(float4*)&task_out[(size_t)tG*64 + c] = x;
    atomicAdd(&mtp[c+0], x.x);
    atomicAdd(&mtp[c+1], x.y);
    atomicAdd(&mtp[c+2], x.z);
    atomicAdd(&mtp[c+3], x.w);
    __syncthreads();
    if (tid < 64) ws[O_MTPP + wpar*256 + (bid - NOPB)*64 + tid] = mtp[tid];
  }
}

// ------------- final head: out[i,t] = a_i + b_e + c_t + bias -------------
__global__ __launch_bounds__(256) void k_final(
    const float* __restrict__ opF, const float* __restrict__ taskF,
    const float* __restrict__ finalW, const float* __restrict__ finalb,
    const float* __restrict__ bplace, float* __restrict__ out)
{
  __shared__ float sTask[4096];
  __shared__ float cvec[64];
  const int tid = threadIdx.x;
  for (int i = tid*4; i < 4096; i += 1024)
    *(float4*)&sTask[i] = *(const float4*)&taskF[i];
  __syncthreads();
  const int lane = tid & 63;
  const int wave = tid >> 6;
  const float w2 = finalW[72 + lane];
  for (int jt = 0; jt < 16; ++jt) {
    const int t = wave*16 + jt;
    float v = sTask[t*64 + lane]*w2;
    for (int m = 32; m >= 1; m >>= 1) v += __shfl_xor(v, m, 64);
    if (lane == 0) cvec[t] = v;
  }
  __syncthreads();
  const int e = blockIdx.x*256 + tid;
  float v = opF[e]*finalW[lane];
  for (int m = 32; m >= 1; m >>= 1) v += __shfl_xor(v, m, 64);
  out[e] = v + bplace[e] + cvec[lane] + finalb[0];
}

extern "C" void kernel_launch(void* const* d_in, const int* in_sizes, int n_in,
                              void* d_out, int out_size, void* d_ws, size_t ws_size,
                              hipStream_t stream)
{
  (void)in_sizes; (void)n_in; (void)out_size;
  if (ws_size < (size_t)O_TOTAL * sizeof(float)) return;

  const float* op_feats     = (const float*)d_in[0];
  const float* task_feats   = (const float*)d_in[1];
  const float* tensor_feats = (const float*)d_in[2];
  const float* link_feats   = (const float*)d_in[3];
  const float* place_feats  = (const float*)d_in[4];
  const int*   prev_src     = (const int*)d_in[5];
  const int*   prev_dst     = (const int*)d_in[6];
  const int*   link_src     = (const int*)d_in[7];
  const int*   link_dst     = (const int*)d_in[8];
  const float* op_W         = (const float*)d_in[9];
  const float* op_b         = (const float*)d_in[10];
  const float* task_W       = (const float*)d_in[11];
  const float* task_b       = (const float*)d_in[12];
  const float* eW           = (const float*)d_in[13];
  const float* eb           = (const float*)d_in[14];
  const float* gW           = (const float*)d_in[15];
  const float* gb           = (const float*)d_in[16];
  const float* finalW       = (const float*)d_in[17];
  const float* finalb       = (const float*)d_in[18];
  float* w = (float*)d_ws;
  float* out = (float*)d_out;

  // task_embed first: it also zeroes the count arrays used by k_edge_pass1
  k_task_embed<<<1, 256, 0, stream>>>(task_feats, task_W, task_b,
                                      w + O_TASK_A, w + O_MTPP, w);
  k_op_embed<<<256, 256, 0, stream>>>(op_feats, op_W, op_b, w + O_OP_A, w + O_MOPP);
  k_edge_pass1<<<128, 256, 0, stream>>>(tensor_feats, link_feats, prev_src, prev_dst,
                                        link_src, link_dst, eW, eb, w);
  k_place<<<256, 256, 0, stream>>>(place_feats, eW, eb, finalW, w);
  k_sef<<<258, 256, 0, stream>>>(w);

  for (int l = 0; l < 6; ++l) {
    const float* oin  = w + ((l & 1) ? O_OP_B : O_OP_A);
    float*       oout = w + ((l & 1) ? O_OP_A : O_OP_B);
    const float* tin  = w + ((l & 1) ? O_TASK_B : O_TASK_A);
    float*       tout = w + ((l & 1) ? O_TASK_A : O_TASK_B);
    k_layer<<<NOPB + 4, 256, 0, stream>>>(l, gW, gb, oin, oout, tin, tout, w);
  }

  k_final<<<1024, 256, 0, stream>>>(w + O_OP_A, w + O_TASK_A, finalW, finalb,
                                    w + O_BPLACE, out);
}